// Round 1
// baseline (5687.066 us; speedup 1.0000x reference)
//
#include <hip/hip_runtime.h>

#define NNODES 100000
#define NEDGES 1600000
#define DH 64
#define NG 512
#define DOUT 10
#define EPSV 1e-5f

// ---------------------------------------------------------------- init
__global__ void k_init(float* __restrict__ dinv, float* __restrict__ pooled,
                       float* __restrict__ cnt) {
    int i = blockIdx.x * 256 + threadIdx.x;
    if (i < NNODES) dinv[i] = 1.0f;          // self-loop contributes 1 to degree
    if (i < NG * DH) pooled[i] = 0.0f;
    if (i < NG) cnt[i] = 0.0f;
}

// degree accumulation over dst
__global__ void k_deg(const int* __restrict__ dstE, float* __restrict__ dinv) {
    int e = blockIdx.x * 256 + threadIdx.x;
    if (e < NEDGES) unsafeAtomicAdd(&dinv[dstE[e]], 1.0f);
}

__global__ void k_rsqrt(float* __restrict__ dinv) {
    int i = blockIdx.x * 256 + threadIdx.x;
    if (i < NNODES) dinv[i] = rsqrtf(dinv[i]);   // deg >= 1 always
}

// ---------------------------------------------------------------- GEMM h = act(in) @ W
// block = 256 threads, 16 rows/block. W (64x64) + input tile in LDS.
// AFFINE: apply y = relu(v*scale[c]+shift[c]) on load (fused BN+ReLU of previous layer).
template <int AFFINE>
__global__ void k_gemm(const float* __restrict__ in, const float* __restrict__ W,
                       const float* __restrict__ scale, const float* __restrict__ shift,
                       float* __restrict__ out) {
    __shared__ float Wl[64 * 64];
    __shared__ float inl[16 * 64];
    const int tid = threadIdx.x;
    const int c = tid & 63, rg = tid >> 6;

#pragma unroll
    for (int j = 0; j < 16; ++j) Wl[tid + j * 256] = W[tid + j * 256];

    const int base = blockIdx.x * 16;
#pragma unroll
    for (int j = 0; j < 4; ++j) {
        int idx = tid + j * 256;
        int r = idx >> 6, col = idx & 63;
        int gr = base + r;
        float v = (gr < NNODES) ? in[(size_t)gr * 64 + col] : 0.0f;
        if (AFFINE) v = fmaxf(fmaf(v, scale[col], shift[col]), 0.0f);
        inl[idx] = v;
    }
    __syncthreads();

    float acc0 = 0.f, acc1 = 0.f, acc2 = 0.f, acc3 = 0.f;
    const float* ip = &inl[rg * 4 * 64];
#pragma unroll
    for (int k = 0; k < 64; k += 4) {
        float4 a0 = *(const float4*)(ip + 0 * 64 + k);
        float4 a1 = *(const float4*)(ip + 1 * 64 + k);
        float4 a2 = *(const float4*)(ip + 2 * 64 + k);
        float4 a3 = *(const float4*)(ip + 3 * 64 + k);
        float w0 = Wl[(k + 0) * 64 + c];
        float w1 = Wl[(k + 1) * 64 + c];
        float w2 = Wl[(k + 2) * 64 + c];
        float w3 = Wl[(k + 3) * 64 + c];
        acc0 = fmaf(a0.w, w3, fmaf(a0.z, w2, fmaf(a0.y, w1, fmaf(a0.x, w0, acc0))));
        acc1 = fmaf(a1.w, w3, fmaf(a1.z, w2, fmaf(a1.y, w1, fmaf(a1.x, w0, acc1))));
        acc2 = fmaf(a2.w, w3, fmaf(a2.z, w2, fmaf(a2.y, w1, fmaf(a2.x, w0, acc2))));
        acc3 = fmaf(a3.w, w3, fmaf(a3.z, w2, fmaf(a3.y, w1, fmaf(a3.x, w0, acc3))));
    }
    const int r0 = base + rg * 4;
    if (r0 + 0 < NNODES) out[(size_t)(r0 + 0) * 64 + c] = acc0;
    if (r0 + 1 < NNODES) out[(size_t)(r0 + 1) * 64 + c] = acc1;
    if (r0 + 2 < NNODES) out[(size_t)(r0 + 2) * 64 + c] = acc2;
    if (r0 + 3 < NNODES) out[(size_t)(r0 + 3) * 64 + c] = acc3;
}

// agg[i][c] = bias[c] + h[i][c] * dinv[i]^2   (self-loop term), also zero BN stats
__global__ void k_initagg(const float* __restrict__ h, const float* __restrict__ bias,
                          const float* __restrict__ dinv, float* __restrict__ agg,
                          float* __restrict__ stats) {
    if (blockIdx.x == 0 && threadIdx.x < 128) stats[threadIdx.x] = 0.0f;
    int t = blockIdx.x * 256 + threadIdx.x;
    if (t < NNODES * DH) {
        int i = t >> 6, c = t & 63;
        float dv = dinv[i];
        agg[t] = fmaf(h[t], dv * dv, bias[c]);
    }
}

// scatter: agg[dst] += norm * h[src], 16 lanes per edge, float4 per lane
__global__ void k_scatter(const float* __restrict__ h, const int* __restrict__ srcE,
                          const int* __restrict__ dstE, const float* __restrict__ dinv,
                          float* __restrict__ agg) {
    int t = blockIdx.x * 256 + threadIdx.x;
    int e = t >> 4, q = t & 15;
    if (e >= NEDGES) return;
    int s = srcE[e], d = dstE[e];
    float nm = dinv[s] * dinv[d];
    float4 hv = ((const float4*)h)[(size_t)s * 16 + q];
    float* ap = agg + (size_t)d * 64 + q * 4;
    unsafeAtomicAdd(ap + 0, hv.x * nm);
    unsafeAtomicAdd(ap + 1, hv.y * nm);
    unsafeAtomicAdd(ap + 2, hv.z * nm);
    unsafeAtomicAdd(ap + 3, hv.w * nm);
}

// per-feature sum / sumsq over N rows
__global__ void k_stats(const float* __restrict__ agg, float* __restrict__ stats) {
    const int c = threadIdx.x & 63, rg = threadIdx.x >> 2 >> 4;  // rg = tid>>6
    float s = 0.f, ss = 0.f;
    for (int r = blockIdx.x * 4 + (threadIdx.x >> 6); r < NNODES; r += gridDim.x * 4) {
        float v = agg[(size_t)r * 64 + c];
        s += v;
        ss = fmaf(v, v, ss);
    }
    __shared__ float ls[256], lss[256];
    ls[threadIdx.x] = s;
    lss[threadIdx.x] = ss;
    __syncthreads();
    if (threadIdx.x < 64) {
        s = ls[c] + ls[c + 64] + ls[c + 128] + ls[c + 192];
        ss = lss[c] + lss[c + 64] + lss[c + 128] + lss[c + 192];
        unsafeAtomicAdd(&stats[c], s);
        unsafeAtomicAdd(&stats[64 + c], ss);
    }
    (void)rg;
}

// scale/shift from stats: y = x*scale + shift == (x-mu)*rsqrt(var+eps)*g + be
__global__ void k_bnparams(const float* __restrict__ stats, const float* __restrict__ g,
                           const float* __restrict__ be, float* __restrict__ scale,
                           float* __restrict__ shift) {
    int c = threadIdx.x;
    if (c < 64) {
        float mu = stats[c] * (1.0f / NNODES);
        float var = stats[64 + c] * (1.0f / NNODES) - mu * mu;
        float sc = g[c] * rsqrtf(var + EPSV);
        scale[c] = sc;
        shift[c] = fmaf(-mu, sc, be[c]);
    }
}

// pool: relu(bn(agg)) atomically accumulated per graph + counts
__global__ void k_pool(const float* __restrict__ agg, const float* __restrict__ scale,
                       const float* __restrict__ shift, const int* __restrict__ batch,
                       float* __restrict__ pooled, float* __restrict__ cnt) {
    int t = blockIdx.x * 256 + threadIdx.x;
    if (t >= NNODES * DH) return;
    int i = t >> 6, c = t & 63;
    float v = fmaxf(fmaf(agg[t], scale[c], shift[c]), 0.0f);
    int g = batch[i];
    unsafeAtomicAdd(&pooled[(size_t)g * 64 + c], v);
    if (c == 0) unsafeAtomicAdd(&cnt[g], 1.0f);
}

// out[g][o] = bfc[o] + sum_c pooled[g][c]/max(cnt,1) * Wfc[c][o]
__global__ void k_final(const float* __restrict__ pooled, const float* __restrict__ cnt,
                        const float* __restrict__ Wfc, const float* __restrict__ bfc,
                        float* __restrict__ out) {
    __shared__ float p[64];
    __shared__ float ic;
    int g = blockIdx.x, tid = threadIdx.x;
    p[tid] = pooled[(size_t)g * 64 + tid];
    if (tid == 0) ic = 1.0f / fmaxf(cnt[g], 1.0f);
    __syncthreads();
    if (tid < DOUT) {
        float a = bfc[tid];
#pragma unroll 8
        for (int c = 0; c < 64; ++c) a = fmaf(p[c] * ic, Wfc[c * DOUT + tid], a);
        out[g * DOUT + tid] = a;
    }
}

extern "C" void kernel_launch(void* const* d_in, const int* in_sizes, int n_in,
                              void* d_out, int out_size, void* d_ws, size_t ws_size,
                              hipStream_t stream) {
    const float* x = (const float*)d_in[0];
    const int* ei = (const int*)d_in[1];
    const int* batch = (const int*)d_in[2];
    const int* srcE = ei;            // edge_index[0]
    const int* dstE = ei + NEDGES;   // edge_index[1]
    const float* W[3] = {(const float*)d_in[3], (const float*)d_in[7], (const float*)d_in[11]};
    const float* B[3] = {(const float*)d_in[4], (const float*)d_in[8], (const float*)d_in[12]};
    const float* Gm[3] = {(const float*)d_in[5], (const float*)d_in[9], (const float*)d_in[13]};
    const float* Be[3] = {(const float*)d_in[6], (const float*)d_in[10], (const float*)d_in[14]};
    const float* Wfc = (const float*)d_in[15];
    const float* bfc = (const float*)d_in[16];
    float* out = (float*)d_out;

    float* f = (float*)d_ws;
    float* dinv   = f;                    // N (degree then rsqrt in place)
    float* h      = f + 131072;           // N*64
    float* agg    = h + (size_t)NNODES * DH;   // N*64
    float* stats  = agg + (size_t)NNODES * DH; // 128 (sum, sumsq)
    float* scale  = stats + 128;          // 64
    float* shift  = scale + 64;           // 64
    float* pooled = shift + 64;           // 512*64
    float* cnt    = pooled + NG * DH;     // 512

    k_init<<<(NNODES + 255) / 256, 256, 0, stream>>>(dinv, pooled, cnt);
    k_deg<<<(NEDGES + 255) / 256, 256, 0, stream>>>(dstE, dinv);
    k_rsqrt<<<(NNODES + 255) / 256, 256, 0, stream>>>(dinv);

    for (int l = 0; l < 3; ++l) {
        const float* in = (l == 0) ? x : agg;
        if (l == 0)
            k_gemm<0><<<(NNODES + 15) / 16, 256, 0, stream>>>(in, W[l], scale, shift, h);
        else
            k_gemm<1><<<(NNODES + 15) / 16, 256, 0, stream>>>(in, W[l], scale, shift, h);
        k_initagg<<<(NNODES * DH + 255) / 256, 256, 0, stream>>>(h, B[l], dinv, agg, stats);
        k_scatter<<<(NEDGES * 16 + 255) / 256, 256, 0, stream>>>(h, srcE, dstE, dinv, agg);
        k_stats<<<512, 256, 0, stream>>>(agg, stats);
        k_bnparams<<<1, 64, 0, stream>>>(stats, Gm[l], Be[l], scale, shift);
    }

    k_pool<<<(NNODES * DH + 255) / 256, 256, 0, stream>>>(agg, scale, shift, batch, pooled, cnt);
    k_final<<<NG, 64, 0, stream>>>(pooled, cnt, Wfc, bfc, out);
}

// Round 3
// 2183.143 us; speedup vs baseline: 2.6050x; 2.6050x over previous
//
#include <hip/hip_runtime.h>

#define NNODES 100000
#define NEDGES 1600000
#define DH 64
#define NG 512
#define DOUT 10
#define EPSV 1e-5f

// ---------------------------------------------------------------- common small kernels

// zero: cntdeg (int), pooled, cnt
__global__ void k_zero(int* __restrict__ cntdeg, float* __restrict__ pooled,
                       float* __restrict__ cnt) {
    int i = blockIdx.x * 256 + threadIdx.x;
    if (i < NNODES) cntdeg[i] = 0;
    if (i < NG * DH) pooled[i] = 0.0f;
    if (i < NG) cnt[i] = 0.0f;
}

__global__ void k_zstat(float* __restrict__ stats) {
    if (threadIdx.x < 128) stats[threadIdx.x] = 0.0f;
}

// histogram of dst
__global__ void k_count(const int* __restrict__ dstE, int* __restrict__ cntdeg) {
    int e = blockIdx.x * 256 + threadIdx.x;
    if (e < NEDGES) atomicAdd(&cntdeg[dstE[e]], 1);
}

// dinv = rsqrt(1 + in_degree)   (self-loop contributes 1)
__global__ void k_dinv(const int* __restrict__ cntdeg, float* __restrict__ dinv) {
    int i = blockIdx.x * 256 + threadIdx.x;
    if (i < NNODES) dinv[i] = rsqrtf(1.0f + (float)cntdeg[i]);
}

// single-block exclusive scan of cntdeg -> rowptr, cursor
__global__ void __launch_bounds__(1024) k_scan(const int* __restrict__ cntdeg,
                                               int* __restrict__ rowptr,
                                               int* __restrict__ cursor) {
    __shared__ int ps[1024];
    const int t = threadIdx.x;
    const int CH = (NNODES + 1023) / 1024;
    const int beg = t * CH;
    const int end = (beg + CH < NNODES) ? beg + CH : NNODES;
    int s = 0;
    for (int i = beg; i < end; ++i) s += cntdeg[i];
    ps[t] = s;
    __syncthreads();
    for (int off = 1; off < 1024; off <<= 1) {
        int v = (t >= off) ? ps[t - off] : 0;
        __syncthreads();
        ps[t] += v;
        __syncthreads();
    }
    int run = (t > 0) ? ps[t - 1] : 0;
    for (int i = beg; i < end; ++i) {
        rowptr[i] = run;
        cursor[i] = run;
        run += cntdeg[i];
    }
    if (t == 1023) rowptr[NNODES] = run;
}

// fill CSR slots: csr[pos] = {src, norm}
__global__ void k_fill(const int* __restrict__ srcE, const int* __restrict__ dstE,
                       const float* __restrict__ dinv, int* __restrict__ cursor,
                       int2* __restrict__ csr) {
    int e = blockIdx.x * 256 + threadIdx.x;
    if (e >= NEDGES) return;
    int s = srcE[e], d = dstE[e];
    int pos = atomicAdd(&cursor[d], 1);
    float nm = dinv[s] * dinv[d];
    csr[pos] = make_int2(s, __float_as_int(nm));
}

// ---------------------------------------------------------------- GEMM h = act(in) @ W
template <int AFFINE>
__global__ void k_gemm(const float* __restrict__ in, const float* __restrict__ W,
                       const float* __restrict__ scale, const float* __restrict__ shift,
                       float* __restrict__ out) {
    __shared__ float Wl[64 * 64];
    __shared__ float inl[16 * 64];
    const int tid = threadIdx.x;
    const int c = tid & 63, rg = tid >> 6;

#pragma unroll
    for (int j = 0; j < 16; ++j) Wl[tid + j * 256] = W[tid + j * 256];

    const int base = blockIdx.x * 16;
#pragma unroll
    for (int j = 0; j < 4; ++j) {
        int idx = tid + j * 256;
        int r = idx >> 6, col = idx & 63;
        int gr = base + r;
        float v = (gr < NNODES) ? in[(size_t)gr * 64 + col] : 0.0f;
        if (AFFINE) v = fmaxf(fmaf(v, scale[col], shift[col]), 0.0f);
        inl[idx] = v;
    }
    __syncthreads();

    float acc0 = 0.f, acc1 = 0.f, acc2 = 0.f, acc3 = 0.f;
    const float* ip = &inl[rg * 4 * 64];
#pragma unroll
    for (int k = 0; k < 64; k += 4) {
        float4 a0 = *(const float4*)(ip + 0 * 64 + k);
        float4 a1 = *(const float4*)(ip + 1 * 64 + k);
        float4 a2 = *(const float4*)(ip + 2 * 64 + k);
        float4 a3 = *(const float4*)(ip + 3 * 64 + k);
        float w0 = Wl[(k + 0) * 64 + c];
        float w1 = Wl[(k + 1) * 64 + c];
        float w2 = Wl[(k + 2) * 64 + c];
        float w3 = Wl[(k + 3) * 64 + c];
        acc0 = fmaf(a0.w, w3, fmaf(a0.z, w2, fmaf(a0.y, w1, fmaf(a0.x, w0, acc0))));
        acc1 = fmaf(a1.w, w3, fmaf(a1.z, w2, fmaf(a1.y, w1, fmaf(a1.x, w0, acc1))));
        acc2 = fmaf(a2.w, w3, fmaf(a2.z, w2, fmaf(a2.y, w1, fmaf(a2.x, w0, acc2))));
        acc3 = fmaf(a3.w, w3, fmaf(a3.z, w2, fmaf(a3.y, w1, fmaf(a3.x, w0, acc3))));
    }
    const int r0 = base + rg * 4;
    if (r0 + 0 < NNODES) out[(size_t)(r0 + 0) * 64 + c] = acc0;
    if (r0 + 1 < NNODES) out[(size_t)(r0 + 1) * 64 + c] = acc1;
    if (r0 + 2 < NNODES) out[(size_t)(r0 + 2) * 64 + c] = acc2;
    if (r0 + 3 < NNODES) out[(size_t)(r0 + 3) * 64 + c] = acc3;
}

// ---------------------------------------------------------------- gather (CSR) aggregation
// agg[i] = bias + dinv[i]^2 * h[i] + sum_{e in CSR[i]} norm_e * h[src_e]
// 16 lanes per node, float4 per lane.
__global__ void k_gather(const float* __restrict__ h, const int2* __restrict__ csr,
                         const int* __restrict__ rowptr, const float* __restrict__ dinv,
                         const float* __restrict__ bias, float* __restrict__ agg) {
    int t = blockIdx.x * 256 + threadIdx.x;
    int i = t >> 4, q = t & 15;
    if (i >= NNODES) return;
    const float4* h4 = (const float4*)h;
    float dv = dinv[i];
    float sn = dv * dv;
    float4 a = h4[(size_t)i * 16 + q];
    float4 bq = ((const float4*)bias)[q];
    float4 acc;
    acc.x = fmaf(a.x, sn, bq.x);
    acc.y = fmaf(a.y, sn, bq.y);
    acc.z = fmaf(a.z, sn, bq.z);
    acc.w = fmaf(a.w, sn, bq.w);
    int e0 = rowptr[i], e1 = rowptr[i + 1];
    for (int e = e0; e < e1; ++e) {
        int2 en = csr[e];
        float nm = __int_as_float(en.y);
        float4 hv = h4[(size_t)en.x * 16 + q];
        acc.x = fmaf(hv.x, nm, acc.x);
        acc.y = fmaf(hv.y, nm, acc.y);
        acc.z = fmaf(hv.z, nm, acc.z);
        acc.w = fmaf(hv.w, nm, acc.w);
    }
    ((float4*)agg)[(size_t)i * 16 + q] = acc;
}

// ---------------------------------------------------------------- BN stats / params
__global__ void k_stats(const float* __restrict__ agg, float* __restrict__ stats) {
    const int c = threadIdx.x & 63;
    float s = 0.f, ss = 0.f;
    for (int r = blockIdx.x * 4 + (threadIdx.x >> 6); r < NNODES; r += gridDim.x * 4) {
        float v = agg[(size_t)r * 64 + c];
        s += v;
        ss = fmaf(v, v, ss);
    }
    __shared__ float ls[256], lss[256];
    ls[threadIdx.x] = s;
    lss[threadIdx.x] = ss;
    __syncthreads();
    if (threadIdx.x < 64) {
        s = ls[c] + ls[c + 64] + ls[c + 128] + ls[c + 192];
        ss = lss[c] + lss[c + 64] + lss[c + 128] + lss[c + 192];
        unsafeAtomicAdd(&stats[c], s);
        unsafeAtomicAdd(&stats[64 + c], ss);
    }
}

__global__ void k_bnparams(const float* __restrict__ stats, const float* __restrict__ g,
                           const float* __restrict__ be, float* __restrict__ scale,
                           float* __restrict__ shift) {
    int c = threadIdx.x;
    if (c < 64) {
        float mu = stats[c] * (1.0f / NNODES);
        float var = stats[64 + c] * (1.0f / NNODES) - mu * mu;
        float sc = g[c] * rsqrtf(var + EPSV);
        scale[c] = sc;
        shift[c] = fmaf(-mu, sc, be[c]);
    }
}

// ---------------------------------------------------------------- pool + final
__global__ void k_pool(const float* __restrict__ agg, const float* __restrict__ scale,
                       const float* __restrict__ shift, const int* __restrict__ batch,
                       float* __restrict__ pooled, float* __restrict__ cnt) {
    int t = blockIdx.x * 256 + threadIdx.x;
    if (t >= NNODES * DH) return;
    int i = t >> 6, c = t & 63;
    float v = fmaxf(fmaf(agg[t], scale[c], shift[c]), 0.0f);
    int g = batch[i];
    unsafeAtomicAdd(&pooled[(size_t)g * 64 + c], v);
    if (c == 0) unsafeAtomicAdd(&cnt[g], 1.0f);
}

__global__ void k_final(const float* __restrict__ pooled, const float* __restrict__ cnt,
                        const float* __restrict__ Wfc, const float* __restrict__ bfc,
                        float* __restrict__ out) {
    __shared__ float p[64];
    __shared__ float ic;
    int g = blockIdx.x, tid = threadIdx.x;
    p[tid] = pooled[(size_t)g * 64 + tid];
    if (tid == 0) ic = 1.0f / fmaxf(cnt[g], 1.0f);
    __syncthreads();
    if (tid < DOUT) {
        float a = bfc[tid];
#pragma unroll 8
        for (int c = 0; c < 64; ++c) a = fmaf(p[c] * ic, Wfc[c * DOUT + tid], a);
        out[g * DOUT + tid] = a;
    }
}

// ---------------------------------------------------------------- fallback scatter path
__global__ void k_initf(float* __restrict__ dinv, float* __restrict__ pooled,
                        float* __restrict__ cnt) {
    int i = blockIdx.x * 256 + threadIdx.x;
    if (i < NNODES) dinv[i] = 1.0f;
    if (i < NG * DH) pooled[i] = 0.0f;
    if (i < NG) cnt[i] = 0.0f;
}
__global__ void k_degf(const int* __restrict__ dstE, float* __restrict__ dinv) {
    int e = blockIdx.x * 256 + threadIdx.x;
    if (e < NEDGES) unsafeAtomicAdd(&dinv[dstE[e]], 1.0f);
}
__global__ void k_rsqrtf(float* __restrict__ dinv) {
    int i = blockIdx.x * 256 + threadIdx.x;
    if (i < NNODES) dinv[i] = rsqrtf(dinv[i]);
}
__global__ void k_initagg(const float* __restrict__ h, const float* __restrict__ bias,
                          const float* __restrict__ dinv, float* __restrict__ agg,
                          float* __restrict__ stats) {
    if (blockIdx.x == 0 && threadIdx.x < 128) stats[threadIdx.x] = 0.0f;
    int t = blockIdx.x * 256 + threadIdx.x;
    if (t < NNODES * DH) {
        int i = t >> 6, c = t & 63;
        float dv = dinv[i];
        agg[t] = fmaf(h[t], dv * dv, bias[c]);
    }
}
__global__ void k_scatter(const float* __restrict__ h, const int* __restrict__ srcE,
                          const int* __restrict__ dstE, const float* __restrict__ dinv,
                          float* __restrict__ agg) {
    int t = blockIdx.x * 256 + threadIdx.x;
    int e = t >> 4, q = t & 15;
    if (e >= NEDGES) return;
    int s = srcE[e], d = dstE[e];
    float nm = dinv[s] * dinv[d];
    float4 hv = ((const float4*)h)[(size_t)s * 16 + q];
    float* ap = agg + (size_t)d * 64 + q * 4;
    unsafeAtomicAdd(ap + 0, hv.x * nm);
    unsafeAtomicAdd(ap + 1, hv.y * nm);
    unsafeAtomicAdd(ap + 2, hv.z * nm);
    unsafeAtomicAdd(ap + 3, hv.w * nm);
}

// ---------------------------------------------------------------- launch
extern "C" void kernel_launch(void* const* d_in, const int* in_sizes, int n_in,
                              void* d_out, int out_size, void* d_ws, size_t ws_size,
                              hipStream_t stream) {
    const float* x = (const float*)d_in[0];
    const int* ei = (const int*)d_in[1];
    const int* batch = (const int*)d_in[2];
    const int* srcE = ei;
    const int* dstE = ei + NEDGES;
    const float* W[3] = {(const float*)d_in[3], (const float*)d_in[7], (const float*)d_in[11]};
    const float* B[3] = {(const float*)d_in[4], (const float*)d_in[8], (const float*)d_in[12]};
    const float* Gm[3] = {(const float*)d_in[5], (const float*)d_in[9], (const float*)d_in[13]};
    const float* Be[3] = {(const float*)d_in[6], (const float*)d_in[10], (const float*)d_in[14]};
    const float* Wfc = (const float*)d_in[15];
    const float* bfc = (const float*)d_in[16];
    float* out = (float*)d_out;

    // CSR layout (all offsets 16B-aligned)
    float* f = (float*)d_ws;
    float* dinv = f;                            // 100000
    int* cntdeg = (int*)(f + 100000);           // 100000
    int* rowptr = (int*)(f + 200000);           // 100016 (padded)
    int* cursor = (int*)(f + 300016);           // 100000
    int2* csr = (int2*)(f + 400016);            // 1.6M int2 = 3.2M ints
    float* h = f + 3600016;                     // 6.4M
    float* agg = h + (size_t)NNODES * DH;       // 6.4M
    float* stats = agg + (size_t)NNODES * DH;   // 128
    float* scale = stats + 128;                 // 64
    float* shift = scale + 64;                  // 64
    float* pooled = shift + 64;                 // 32768
    float* cnt = pooled + NG * DH;              // 512
    const size_t need_csr = (size_t)(3600016 + 6400000 * 2 + 128 + 64 + 64 + 32768 + 512) * 4;

    const bool use_csr = ws_size >= need_csr;

    if (use_csr) {
        k_zero<<<(NNODES + 255) / 256, 256, 0, stream>>>(cntdeg, pooled, cnt);
        k_count<<<(NEDGES + 255) / 256, 256, 0, stream>>>(dstE, cntdeg);
        k_dinv<<<(NNODES + 255) / 256, 256, 0, stream>>>(cntdeg, dinv);
        k_scan<<<1, 1024, 0, stream>>>(cntdeg, rowptr, cursor);
        k_fill<<<(NEDGES + 255) / 256, 256, 0, stream>>>(srcE, dstE, dinv, cursor, csr);

        for (int l = 0; l < 3; ++l) {
            const float* in = (l == 0) ? x : agg;
            if (l == 0)
                k_gemm<0><<<(NNODES + 15) / 16, 256, 0, stream>>>(in, W[l], scale, shift, h);
            else
                k_gemm<1><<<(NNODES + 15) / 16, 256, 0, stream>>>(in, W[l], scale, shift, h);
            k_gather<<<(NNODES * 16 + 255) / 256, 256, 0, stream>>>(h, csr, rowptr, dinv, B[l], agg);
            k_zstat<<<1, 128, 0, stream>>>(stats);
            k_stats<<<512, 256, 0, stream>>>(agg, stats);
            k_bnparams<<<1, 64, 0, stream>>>(stats, Gm[l], Be[l], scale, shift);
        }
    } else {
        // fallback: round-1 verified atomic-scatter path (smaller ws footprint)
        float* fdinv = f;                         // reserve 131072
        float* fh = f + 131072;
        float* fagg = fh + (size_t)NNODES * DH;
        float* fstats = fagg + (size_t)NNODES * DH;
        float* fscale = fstats + 128;
        float* fshift = fscale + 64;
        float* fpooled = fshift + 64;
        float* fcnt = fpooled + NG * DH;
        h = fh; agg = fagg; stats = fstats; scale = fscale; shift = fshift;
        pooled = fpooled; cnt = fcnt; dinv = fdinv;

        k_initf<<<(NNODES + 255) / 256, 256, 0, stream>>>(dinv, pooled, cnt);
        k_degf<<<(NEDGES + 255) / 256, 256, 0, stream>>>(dstE, dinv);
        k_rsqrtf<<<(NNODES + 255) / 256, 256, 0, stream>>>(dinv);
        for (int l = 0; l < 3; ++l) {
            const float* in = (l == 0) ? x : agg;
            if (l == 0)
                k_gemm<0><<<(NNODES + 15) / 16, 256, 0, stream>>>(in, W[l], scale, shift, h);
            else
                k_gemm<1><<<(NNODES + 15) / 16, 256, 0, stream>>>(in, W[l], scale, shift, h);
            k_initagg<<<(NNODES * DH + 255) / 256, 256, 0, stream>>>(h, B[l], dinv, agg, stats);
            k_scatter<<<(NEDGES * 16 + 255) / 256, 256, 0, stream>>>(h, srcE, dstE, dinv, agg);
            k_stats<<<512, 256, 0, stream>>>(agg, stats);
            k_bnparams<<<1, 64, 0, stream>>>(stats, Gm[l], Be[l], scale, shift);
        }
    }

    k_pool<<<(NNODES * DH + 255) / 256, 256, 0, stream>>>(agg, scale, shift, batch, pooled, cnt);
    k_final<<<NG, 64, 0, stream>>>(pooled, cnt, Wfc, bfc, out);
}

// Round 4
// 1064.919 us; speedup vs baseline: 5.3404x; 2.0501x over previous
//
#include <hip/hip_runtime.h>

#define NNODES 100000
#define NEDGES 1600000
#define DH 64
#define NG 512
#define DOUT 10
#define EPSV 1e-5f

typedef short bf16x8 __attribute__((ext_vector_type(8)));
typedef float f32x4 __attribute__((ext_vector_type(4)));

__device__ inline unsigned bf16_rne(float x) {
    unsigned u = __float_as_uint(x);
    return (u + 0x7fffu + ((u >> 16) & 1u)) >> 16;
}

// ---------------------------------------------------------------- init / CSR build
__global__ void k_zero(int* __restrict__ cntdeg, float* __restrict__ pooled,
                       float* __restrict__ cnt) {
    int i = blockIdx.x * 256 + threadIdx.x;
    if (i < NNODES) cntdeg[i] = 0;
    if (i < NG * DH) pooled[i] = 0.0f;
    if (i < NG) cnt[i] = 0.0f;
}

__global__ void k_zstat(float* __restrict__ stats) {
    if (threadIdx.x < 128) stats[threadIdx.x] = 0.0f;
}

__global__ void k_count(const int* __restrict__ dstE, int* __restrict__ cntdeg) {
    int e = blockIdx.x * 256 + threadIdx.x;
    if (e < NEDGES) atomicAdd(&cntdeg[dstE[e]], 1);
}

__global__ void k_dinv(const int* __restrict__ cntdeg, float* __restrict__ dinv) {
    int i = blockIdx.x * 256 + threadIdx.x;
    if (i < NNODES) dinv[i] = rsqrtf(1.0f + (float)cntdeg[i]);
}

__global__ void __launch_bounds__(1024) k_scan(const int* __restrict__ cntdeg,
                                               int* __restrict__ rowptr,
                                               int* __restrict__ cursor) {
    __shared__ int ps[1024];
    const int t = threadIdx.x;
    const int CH = (NNODES + 1023) / 1024;
    const int beg = t * CH;
    const int end = (beg + CH < NNODES) ? beg + CH : NNODES;
    int s = 0;
    for (int i = beg; i < end; ++i) s += cntdeg[i];
    ps[t] = s;
    __syncthreads();
    for (int off = 1; off < 1024; off <<= 1) {
        int v = (t >= off) ? ps[t - off] : 0;
        __syncthreads();
        ps[t] += v;
        __syncthreads();
    }
    int run = (t > 0) ? ps[t - 1] : 0;
    for (int i = beg; i < end; ++i) {
        rowptr[i] = run;
        cursor[i] = run;
        run += cntdeg[i];
    }
    if (t == 1023) rowptr[NNODES] = run;
}

__global__ void k_fill(const int* __restrict__ srcE, const int* __restrict__ dstE,
                       const float* __restrict__ dinv, int* __restrict__ cursor,
                       int2* __restrict__ csr) {
    int e = blockIdx.x * 256 + threadIdx.x;
    if (e >= NEDGES) return;
    int s = srcE[e], d = dstE[e];
    int pos = atomicAdd(&cursor[d], 1);
    float nm = dinv[s] * dinv[d];
    csr[pos] = make_int2(s, __float_as_int(nm));
}

// ---------------------------------------------------------------- W fragment prep
// wf per layer: 8192 shorts. hi entries [0,512), lo at +512. entry rem = ct*128+ks*64+lane,
// elem i -> W[k][n], k = ks*32 + (lane>>4)*8 + i, n = ct*16 + (lane&15).
__global__ void k_wprep(const float* __restrict__ W0, const float* __restrict__ W1,
                        const float* __restrict__ W2, short* __restrict__ wf) {
    int t = blockIdx.x * 256 + threadIdx.x;  // [0, 1536)
    if (t >= 1536) return;
    int layer = t >> 9;
    int rem = t & 511;
    int ct = rem >> 7, ks = (rem >> 6) & 1, lane = rem & 63;
    const float* W = (layer == 0) ? W0 : (layer == 1) ? W1 : W2;
    short* hi = wf + layer * 8192 + rem * 8;
    short* lo = hi + 4096;
#pragma unroll
    for (int i = 0; i < 8; ++i) {
        int k = ks * 32 + ((lane >> 4) << 3) + i;
        int n = ct * 16 + (lane & 15);
        float v = W[k * 64 + n];
        unsigned h = bf16_rne(v);
        float fh = __uint_as_float(h << 16);
        unsigned l = bf16_rne(v - fh);
        hi[i] = (short)h;
        lo[i] = (short)l;
    }
}

// ---------------------------------------------------------------- MFMA GEMM
// out[M,64] = act(in[M,64]) @ W. 256 thr = 4 waves, 64 rows/block, wave -> 16 rows.
// hi/lo bf16 split: acc = ah*wh + al*wh + ah*wl  (error ~1e-5, effectively fp32).
template <int AFFINE>
__global__ void __launch_bounds__(256) k_mgemm(const float* __restrict__ in,
        const short* __restrict__ wf, const float* __restrict__ scale,
        const float* __restrict__ shift, float* __restrict__ out) {
    const int tid = threadIdx.x;
    const int wv = tid >> 6, l = tid & 63;
    const int r0 = blockIdx.x * 64 + wv * 16;
    const int row = r0 + (l & 15);
    const int kq = (l >> 4) << 3;  // 0,8,16,24

    float a[2][8];
    if (row < NNODES) {
        const float* rp = in + (size_t)row * 64 + kq;
        *(float4*)&a[0][0] = *(const float4*)(rp);
        *(float4*)&a[0][4] = *(const float4*)(rp + 4);
        *(float4*)&a[1][0] = *(const float4*)(rp + 32);
        *(float4*)&a[1][4] = *(const float4*)(rp + 36);
    } else {
#pragma unroll
        for (int ks = 0; ks < 2; ++ks)
#pragma unroll
            for (int i = 0; i < 8; ++i) a[ks][i] = 0.0f;
    }
    if (AFFINE) {
#pragma unroll
        for (int ks = 0; ks < 2; ++ks) {
            float4 sc0 = *(const float4*)(scale + kq + ks * 32);
            float4 sc1 = *(const float4*)(scale + kq + ks * 32 + 4);
            float4 sh0 = *(const float4*)(shift + kq + ks * 32);
            float4 sh1 = *(const float4*)(shift + kq + ks * 32 + 4);
            a[ks][0] = fmaxf(fmaf(a[ks][0], sc0.x, sh0.x), 0.0f);
            a[ks][1] = fmaxf(fmaf(a[ks][1], sc0.y, sh0.y), 0.0f);
            a[ks][2] = fmaxf(fmaf(a[ks][2], sc0.z, sh0.z), 0.0f);
            a[ks][3] = fmaxf(fmaf(a[ks][3], sc0.w, sh0.w), 0.0f);
            a[ks][4] = fmaxf(fmaf(a[ks][4], sc1.x, sh1.x), 0.0f);
            a[ks][5] = fmaxf(fmaf(a[ks][5], sc1.y, sh1.y), 0.0f);
            a[ks][6] = fmaxf(fmaf(a[ks][6], sc1.z, sh1.z), 0.0f);
            a[ks][7] = fmaxf(fmaf(a[ks][7], sc1.w, sh1.w), 0.0f);
        }
    }

    bf16x8 ah[2], al[2];
#pragma unroll
    for (int ks = 0; ks < 2; ++ks)
#pragma unroll
        for (int i = 0; i < 8; ++i) {
            unsigned h = bf16_rne(a[ks][i]);
            float fh = __uint_as_float(h << 16);
            ah[ks][i] = (short)h;
            al[ks][i] = (short)bf16_rne(a[ks][i] - fh);
        }

    const int rb = r0 + ((l >> 4) << 2);
    const int cb = l & 15;
#pragma unroll
    for (int ct = 0; ct < 4; ++ct) {
        const short* base = wf + (ct * 128 + l) * 8;
        bf16x8 wh0 = *(const bf16x8*)(base);
        bf16x8 wh1 = *(const bf16x8*)(base + 64 * 8);
        bf16x8 wl0 = *(const bf16x8*)(base + 4096);
        bf16x8 wl1 = *(const bf16x8*)(base + 4096 + 64 * 8);
        f32x4 acc = {0.0f, 0.0f, 0.0f, 0.0f};
        acc = __builtin_amdgcn_mfma_f32_16x16x32_bf16(ah[0], wh0, acc, 0, 0, 0);
        acc = __builtin_amdgcn_mfma_f32_16x16x32_bf16(ah[1], wh1, acc, 0, 0, 0);
        acc = __builtin_amdgcn_mfma_f32_16x16x32_bf16(al[0], wh0, acc, 0, 0, 0);
        acc = __builtin_amdgcn_mfma_f32_16x16x32_bf16(al[1], wh1, acc, 0, 0, 0);
        acc = __builtin_amdgcn_mfma_f32_16x16x32_bf16(ah[0], wl0, acc, 0, 0, 0);
        acc = __builtin_amdgcn_mfma_f32_16x16x32_bf16(ah[1], wl1, acc, 0, 0, 0);
        int n = ct * 16 + cb;
#pragma unroll
        for (int r = 0; r < 4; ++r)
            if (rb + r < NNODES) out[(size_t)(rb + r) * 64 + n] = acc[r];
    }
}

// ---------------------------------------------------------------- gather (CSR)
__global__ void k_gather(const float* __restrict__ h, const int2* __restrict__ csr,
                         const int* __restrict__ rowptr, const float* __restrict__ dinv,
                         const float* __restrict__ bias, float* __restrict__ agg) {
    int t = blockIdx.x * 256 + threadIdx.x;
    int i = t >> 4, q = t & 15;
    if (i >= NNODES) return;
    const float4* h4 = (const float4*)h + q;
    float dv = dinv[i];
    float sn = dv * dv;
    float4 a = h4[(size_t)i * 16];
    float4 bq = ((const float4*)bias)[q];
    float ax = fmaf(a.x, sn, bq.x), ay = fmaf(a.y, sn, bq.y);
    float az = fmaf(a.z, sn, bq.z), aw = fmaf(a.w, sn, bq.w);
    float bx = 0.f, by = 0.f, bz = 0.f, bw = 0.f;
    int e0 = rowptr[i], e1 = rowptr[i + 1];
    int e = e0;
    for (; e + 2 <= e1; e += 2) {
        int2 ea = csr[e], eb = csr[e + 1];
        float na = __int_as_float(ea.y), nb = __int_as_float(eb.y);
        float4 ha = h4[(size_t)ea.x * 16];
        float4 hb = h4[(size_t)eb.x * 16];
        ax = fmaf(ha.x, na, ax); ay = fmaf(ha.y, na, ay);
        az = fmaf(ha.z, na, az); aw = fmaf(ha.w, na, aw);
        bx = fmaf(hb.x, nb, bx); by = fmaf(hb.y, nb, by);
        bz = fmaf(hb.z, nb, bz); bw = fmaf(hb.w, nb, bw);
    }
    if (e < e1) {
        int2 ea = csr[e];
        float na = __int_as_float(ea.y);
        float4 ha = h4[(size_t)ea.x * 16];
        ax = fmaf(ha.x, na, ax); ay = fmaf(ha.y, na, ay);
        az = fmaf(ha.z, na, az); aw = fmaf(ha.w, na, aw);
    }
    float4 r;
    r.x = ax + bx; r.y = ay + by; r.z = az + bz; r.w = aw + bw;
    ((float4*)agg)[(size_t)i * 16 + q] = r;
}

// ---------------------------------------------------------------- BN stats / params
__global__ void k_stats(const float* __restrict__ agg, float* __restrict__ stats) {
    const int c = threadIdx.x & 63;
    float s = 0.f, ss = 0.f;
    for (int r = blockIdx.x * 4 + (threadIdx.x >> 6); r < NNODES; r += gridDim.x * 4) {
        float v = agg[(size_t)r * 64 + c];
        s += v;
        ss = fmaf(v, v, ss);
    }
    __shared__ float ls[256], lss[256];
    ls[threadIdx.x] = s;
    lss[threadIdx.x] = ss;
    __syncthreads();
    if (threadIdx.x < 64) {
        s = ls[c] + ls[c + 64] + ls[c + 128] + ls[c + 192];
        ss = lss[c] + lss[c + 64] + lss[c + 128] + lss[c + 192];
        unsafeAtomicAdd(&stats[c], s);
        unsafeAtomicAdd(&stats[64 + c], ss);
    }
}

__global__ void k_bnparams(const float* __restrict__ stats, const float* __restrict__ g,
                           const float* __restrict__ be, float* __restrict__ scale,
                           float* __restrict__ shift) {
    int c = threadIdx.x;
    if (c < 64) {
        float mu = stats[c] * (1.0f / NNODES);
        float var = stats[64 + c] * (1.0f / NNODES) - mu * mu;
        float sc = g[c] * rsqrtf(var + EPSV);
        scale[c] = sc;
        shift[c] = fmaf(-mu, sc, be[c]);
    }
}

// ---------------------------------------------------------------- pool + final
__global__ void k_pool(const float* __restrict__ agg, const float* __restrict__ scale,
                       const float* __restrict__ shift, const int* __restrict__ batch,
                       float* __restrict__ pooled, float* __restrict__ cnt) {
    int t = blockIdx.x * 256 + threadIdx.x;
    if (t >= NNODES * DH) return;
    int i = t >> 6, c = t & 63;
    float v = fmaxf(fmaf(agg[t], scale[c], shift[c]), 0.0f);
    int g = batch[i];
    unsafeAtomicAdd(&pooled[(size_t)g * 64 + c], v);
    if (c == 0) unsafeAtomicAdd(&cnt[g], 1.0f);
}

__global__ void k_final(const float* __restrict__ pooled, const float* __restrict__ cnt,
                        const float* __restrict__ Wfc, const float* __restrict__ bfc,
                        float* __restrict__ out) {
    __shared__ float p[64];
    __shared__ float ic;
    int g = blockIdx.x, tid = threadIdx.x;
    p[tid] = pooled[(size_t)g * 64 + tid];
    if (tid == 0) ic = 1.0f / fmaxf(cnt[g], 1.0f);
    __syncthreads();
    if (tid < DOUT) {
        float a = bfc[tid];
#pragma unroll 8
        for (int c = 0; c < 64; ++c) a = fmaf(p[c] * ic, Wfc[c * DOUT + tid], a);
        out[g * DOUT + tid] = a;
    }
}

// ---------------------------------------------------------------- launch
extern "C" void kernel_launch(void* const* d_in, const int* in_sizes, int n_in,
                              void* d_out, int out_size, void* d_ws, size_t ws_size,
                              hipStream_t stream) {
    const float* x = (const float*)d_in[0];
    const int* ei = (const int*)d_in[1];
    const int* batch = (const int*)d_in[2];
    const int* srcE = ei;
    const int* dstE = ei + NEDGES;
    const float* W[3] = {(const float*)d_in[3], (const float*)d_in[7], (const float*)d_in[11]};
    const float* B[3] = {(const float*)d_in[4], (const float*)d_in[8], (const float*)d_in[12]};
    const float* Gm[3] = {(const float*)d_in[5], (const float*)d_in[9], (const float*)d_in[13]};
    const float* Be[3] = {(const float*)d_in[6], (const float*)d_in[10], (const float*)d_in[14]};
    const float* Wfc = (const float*)d_in[15];
    const float* bfc = (const float*)d_in[16];
    float* out = (float*)d_out;

    float* f = (float*)d_ws;
    float* dinv = f;                            // 100000
    int* cntdeg = (int*)(f + 100000);           // 100000
    int* rowptr = (int*)(f + 200000);           // 100016 (padded)
    int* cursor = (int*)(f + 300016);           // 100000
    int2* csr = (int2*)(f + 400016);            // 1.6M int2
    float* h = f + 3600016;                     // 6.4M
    float* agg = h + (size_t)NNODES * DH;       // 6.4M
    float* stats = agg + (size_t)NNODES * DH;   // 128
    float* scale = stats + 128;                 // 64
    float* shift = scale + 64;                  // 64
    float* pooled = shift + 64;                 // 32768
    float* cnt = pooled + NG * DH;              // 512
    short* wf = (short*)(cnt + NG);             // 3*8192 shorts = 12288 floats

    k_zero<<<(NNODES + 255) / 256, 256, 0, stream>>>(cntdeg, pooled, cnt);
    k_count<<<(NEDGES + 255) / 256, 256, 0, stream>>>(dstE, cntdeg);
    k_dinv<<<(NNODES + 255) / 256, 256, 0, stream>>>(cntdeg, dinv);
    k_scan<<<1, 1024, 0, stream>>>(cntdeg, rowptr, cursor);
    k_fill<<<(NEDGES + 255) / 256, 256, 0, stream>>>(srcE, dstE, dinv, cursor, csr);
    k_wprep<<<6, 256, 0, stream>>>(W[0], W[1], W[2], wf);

    const int gemm_grid = (NNODES + 63) / 64;
    for (int l = 0; l < 3; ++l) {
        const float* in = (l == 0) ? x : agg;
        if (l == 0)
            k_mgemm<0><<<gemm_grid, 256, 0, stream>>>(in, wf + l * 8192, scale, shift, h);
        else
            k_mgemm<1><<<gemm_grid, 256, 0, stream>>>(in, wf + l * 8192, scale, shift, h);
        k_gather<<<(NNODES * 16 + 255) / 256, 256, 0, stream>>>(h, csr, rowptr, dinv, B[l], agg);
        k_zstat<<<1, 128, 0, stream>>>(stats);
        k_stats<<<512, 256, 0, stream>>>(agg, stats);
        k_bnparams<<<1, 64, 0, stream>>>(stats, Gm[l], Be[l], scale, shift);
    }

    k_pool<<<(NNODES * DH + 255) / 256, 256, 0, stream>>>(agg, scale, shift, batch, pooled, cnt);
    k_final<<<NG, 64, 0, stream>>>(pooled, cnt, Wfc, bfc, out);
}

// Round 6
// 819.243 us; speedup vs baseline: 6.9419x; 1.2999x over previous
//
#include <hip/hip_runtime.h>

#define NNODES 100000
#define NEDGES 1600000
#define DH 64
#define NG 512
#define DOUT 10
#define EPSV 1e-5f
#define SCAN_BLKS 391  // ceil(100000/256)

typedef short bf16x8 __attribute__((ext_vector_type(8)));
typedef float f32x4 __attribute__((ext_vector_type(4)));

__device__ inline unsigned bf16_rne(float x) {
    unsigned u = __float_as_uint(x);
    return (u + 0x7fffu + ((u >> 16) & 1u)) >> 16;
}

// ---------------------------------------------------------------- init / CSR build
__global__ void k_zero(int* __restrict__ cntdeg, float* __restrict__ pooled,
                       float* __restrict__ cnt, float* __restrict__ stats) {
    int i = blockIdx.x * 256 + threadIdx.x;
    if (i < NNODES) cntdeg[i] = 0;
    if (i < NG * DH) pooled[i] = 0.0f;
    if (i < NG) cnt[i] = 0.0f;
    if (i < 384) stats[i] = 0.0f;  // 3 layers x (sum,sumsq)
}

__global__ void k_count(const int* __restrict__ dstE, int* __restrict__ cntdeg) {
    int e2 = blockIdx.x * 256 + threadIdx.x;
    if (e2 * 2 + 1 < NEDGES) {
        int2 d = ((const int2*)dstE)[e2];
        atomicAdd(&cntdeg[d.x], 1);
        atomicAdd(&cntdeg[d.y], 1);
    } else if (e2 * 2 < NEDGES) {
        atomicAdd(&cntdeg[dstE[e2 * 2]], 1);
    }
}

// stage 1: per-block sums (+ dinv)
__global__ void k_scan1(const int* __restrict__ cntdeg, int* __restrict__ bsum,
                        float* __restrict__ dinv) {
    __shared__ int ls[256];
    int t = threadIdx.x, i = blockIdx.x * 256 + t;
    int v = (i < NNODES) ? cntdeg[i] : 0;
    if (i < NNODES) dinv[i] = rsqrtf(1.0f + (float)v);
    ls[t] = v;
    __syncthreads();
#pragma unroll
    for (int off = 128; off > 0; off >>= 1) {
        if (t < off) ls[t] += ls[t + off];
        __syncthreads();
    }
    if (t == 0) bsum[blockIdx.x] = ls[0];
}

// stage 2: single-block scan of 391 block sums -> exclusive offsets
__global__ void __launch_bounds__(512) k_scan2(const int* __restrict__ bsum,
                                               int* __restrict__ boff) {
    __shared__ int ps[512];
    int t = threadIdx.x;
    int v = (t < SCAN_BLKS) ? bsum[t] : 0;
    ps[t] = v;
    __syncthreads();
#pragma unroll
    for (int off = 1; off < 512; off <<= 1) {
        int u = (t >= off) ? ps[t - off] : 0;
        __syncthreads();
        ps[t] += u;
        __syncthreads();
    }
    if (t < SCAN_BLKS) boff[t] = ps[t] - v;
}

// stage 3: per-block local scan + offset -> rowptr, cursor
__global__ void k_scan3(const int* __restrict__ cntdeg, const int* __restrict__ boff,
                        int* __restrict__ rowptr, int* __restrict__ cursor) {
    __shared__ int ps[256];
    int t = threadIdx.x, i = blockIdx.x * 256 + t;
    int v = (i < NNODES) ? cntdeg[i] : 0;
    ps[t] = v;
    __syncthreads();
#pragma unroll
    for (int off = 1; off < 256; off <<= 1) {
        int u = (t >= off) ? ps[t - off] : 0;
        __syncthreads();
        ps[t] += u;
        __syncthreads();
    }
    if (i < NNODES) {
        int ex = boff[blockIdx.x] + ps[t] - v;
        rowptr[i] = ex;
        cursor[i] = ex;
    }
    if (i == 0) rowptr[NNODES] = NEDGES;
}

__global__ void k_fill(const int* __restrict__ srcE, const int* __restrict__ dstE,
                       const float* __restrict__ dinv, int* __restrict__ cursor,
                       int2* __restrict__ csr) {
    int e = blockIdx.x * 256 + threadIdx.x;
    if (e >= NEDGES) return;
    int s = srcE[e], d = dstE[e];
    int pos = atomicAdd(&cursor[d], 1);
    float nm = dinv[s] * dinv[d];
    csr[pos] = make_int2(s, __float_as_int(nm));
}

// ---------------------------------------------------------------- W fragment prep
__global__ void k_wprep(const float* __restrict__ W0, const float* __restrict__ W1,
                        const float* __restrict__ W2, short* __restrict__ wf) {
    int t = blockIdx.x * 256 + threadIdx.x;  // [0, 1536)
    if (t >= 1536) return;
    int layer = t >> 9;
    int rem = t & 511;
    int ct = rem >> 7, ks = (rem >> 6) & 1, lane = rem & 63;
    const float* W = (layer == 0) ? W0 : (layer == 1) ? W1 : W2;
    short* hi = wf + layer * 8192 + rem * 8;
    short* lo = hi + 4096;
#pragma unroll
    for (int i = 0; i < 8; ++i) {
        int k = ks * 32 + ((lane >> 4) << 3) + i;
        int n = ct * 16 + (lane & 15);
        float v = W[k * 64 + n];
        unsigned h = bf16_rne(v);
        float fh = __uint_as_float(h << 16);
        unsigned l = bf16_rne(v - fh);
        hi[i] = (short)h;
        lo[i] = (short)l;
    }
}

// ---------------------------------------------------------------- MFMA GEMM
template <int AFFINE>
__global__ void __launch_bounds__(256) k_mgemm(const float* __restrict__ in,
        const short* __restrict__ wf, const float* __restrict__ scale,
        const float* __restrict__ shift, float* __restrict__ out) {
    const int tid = threadIdx.x;
    const int wv = tid >> 6, l = tid & 63;
    const int r0 = blockIdx.x * 64 + wv * 16;
    const int row = r0 + (l & 15);
    const int kq = (l >> 4) << 3;  // 0,8,16,24

    float a[2][8];
    if (row < NNODES) {
        const float* rp = in + (size_t)row * 64 + kq;
        *(float4*)&a[0][0] = *(const float4*)(rp);
        *(float4*)&a[0][4] = *(const float4*)(rp + 4);
        *(float4*)&a[1][0] = *(const float4*)(rp + 32);
        *(float4*)&a[1][4] = *(const float4*)(rp + 36);
    } else {
#pragma unroll
        for (int ks = 0; ks < 2; ++ks)
#pragma unroll
            for (int i = 0; i < 8; ++i) a[ks][i] = 0.0f;
    }
    if (AFFINE) {
#pragma unroll
        for (int ks = 0; ks < 2; ++ks) {
            float4 sc0 = *(const float4*)(scale + kq + ks * 32);
            float4 sc1 = *(const float4*)(scale + kq + ks * 32 + 4);
            float4 sh0 = *(const float4*)(shift + kq + ks * 32);
            float4 sh1 = *(const float4*)(shift + kq + ks * 32 + 4);
            a[ks][0] = fmaxf(fmaf(a[ks][0], sc0.x, sh0.x), 0.0f);
            a[ks][1] = fmaxf(fmaf(a[ks][1], sc0.y, sh0.y), 0.0f);
            a[ks][2] = fmaxf(fmaf(a[ks][2], sc0.z, sh0.z), 0.0f);
            a[ks][3] = fmaxf(fmaf(a[ks][3], sc0.w, sh0.w), 0.0f);
            a[ks][4] = fmaxf(fmaf(a[ks][4], sc1.x, sh1.x), 0.0f);
            a[ks][5] = fmaxf(fmaf(a[ks][5], sc1.y, sh1.y), 0.0f);
            a[ks][6] = fmaxf(fmaf(a[ks][6], sc1.z, sh1.z), 0.0f);
            a[ks][7] = fmaxf(fmaf(a[ks][7], sc1.w, sh1.w), 0.0f);
        }
    }

    bf16x8 ah[2], al[2];
#pragma unroll
    for (int ks = 0; ks < 2; ++ks)
#pragma unroll
        for (int i = 0; i < 8; ++i) {
            unsigned h = bf16_rne(a[ks][i]);
            float fh = __uint_as_float(h << 16);
            ah[ks][i] = (short)h;
            al[ks][i] = (short)bf16_rne(a[ks][i] - fh);
        }

    const int rb = r0 + ((l >> 4) << 2);
    const int cb = l & 15;
#pragma unroll
    for (int ct = 0; ct < 4; ++ct) {
        const short* base = wf + (ct * 128 + l) * 8;
        bf16x8 wh0 = *(const bf16x8*)(base);
        bf16x8 wh1 = *(const bf16x8*)(base + 64 * 8);
        bf16x8 wl0 = *(const bf16x8*)(base + 4096);
        bf16x8 wl1 = *(const bf16x8*)(base + 4096 + 64 * 8);
        f32x4 acc = {0.0f, 0.0f, 0.0f, 0.0f};
        acc = __builtin_amdgcn_mfma_f32_16x16x32_bf16(ah[0], wh0, acc, 0, 0, 0);
        acc = __builtin_amdgcn_mfma_f32_16x16x32_bf16(ah[1], wh1, acc, 0, 0, 0);
        acc = __builtin_amdgcn_mfma_f32_16x16x32_bf16(al[0], wh0, acc, 0, 0, 0);
        acc = __builtin_amdgcn_mfma_f32_16x16x32_bf16(al[1], wh1, acc, 0, 0, 0);
        acc = __builtin_amdgcn_mfma_f32_16x16x32_bf16(ah[0], wl0, acc, 0, 0, 0);
        acc = __builtin_amdgcn_mfma_f32_16x16x32_bf16(ah[1], wl1, acc, 0, 0, 0);
        int n = ct * 16 + cb;
#pragma unroll
        for (int r = 0; r < 4; ++r)
            if (rb + r < NNODES) out[(size_t)(rb + r) * 64 + n] = acc[r];
    }
}

// ---------------------------------------------------------------- gather (CSR), unroll 4
__global__ void k_gather(const float* __restrict__ h, const int2* __restrict__ csr,
                         const int* __restrict__ rowptr, const float* __restrict__ dinv,
                         const float* __restrict__ bias, float* __restrict__ agg) {
    int t = blockIdx.x * 256 + threadIdx.x;
    int i = t >> 4, q = t & 15;
    if (i >= NNODES) return;
    const float4* h4 = (const float4*)h + q;
    float dv = dinv[i];
    float sn = dv * dv;
    float4 a = h4[(size_t)i * 16];
    float4 bq = ((const float4*)bias)[q];
    float A0x = fmaf(a.x, sn, bq.x), A0y = fmaf(a.y, sn, bq.y);
    float A0z = fmaf(a.z, sn, bq.z), A0w = fmaf(a.w, sn, bq.w);
    float A1x = 0.f, A1y = 0.f, A1z = 0.f, A1w = 0.f;
    float A2x = 0.f, A2y = 0.f, A2z = 0.f, A2w = 0.f;
    float A3x = 0.f, A3y = 0.f, A3z = 0.f, A3w = 0.f;
    int e0 = rowptr[i], e1 = rowptr[i + 1];
    int e = e0;
    for (; e + 4 <= e1; e += 4) {
        int2 ea = csr[e], eb = csr[e + 1], ec = csr[e + 2], ed = csr[e + 3];
        float na = __int_as_float(ea.y), nb = __int_as_float(eb.y);
        float nc = __int_as_float(ec.y), nd = __int_as_float(ed.y);
        float4 ha = h4[(size_t)ea.x * 16];
        float4 hb = h4[(size_t)eb.x * 16];
        float4 hc = h4[(size_t)ec.x * 16];
        float4 hd = h4[(size_t)ed.x * 16];
        A0x = fmaf(ha.x, na, A0x); A0y = fmaf(ha.y, na, A0y);
        A0z = fmaf(ha.z, na, A0z); A0w = fmaf(ha.w, na, A0w);
        A1x = fmaf(hb.x, nb, A1x); A1y = fmaf(hb.y, nb, A1y);
        A1z = fmaf(hb.z, nb, A1z); A1w = fmaf(hb.w, nb, A1w);
        A2x = fmaf(hc.x, nc, A2x); A2y = fmaf(hc.y, nc, A2y);
        A2z = fmaf(hc.z, nc, A2z); A2w = fmaf(hc.w, nc, A2w);
        A3x = fmaf(hd.x, nd, A3x); A3y = fmaf(hd.y, nd, A3y);
        A3z = fmaf(hd.z, nd, A3z); A3w = fmaf(hd.w, nd, A3w);
    }
    for (; e + 2 <= e1; e += 2) {
        int2 ea = csr[e], eb = csr[e + 1];
        float na = __int_as_float(ea.y), nb = __int_as_float(eb.y);
        float4 ha = h4[(size_t)ea.x * 16];
        float4 hb = h4[(size_t)eb.x * 16];
        A0x = fmaf(ha.x, na, A0x); A0y = fmaf(ha.y, na, A0y);
        A0z = fmaf(ha.z, na, A0z); A0w = fmaf(ha.w, na, A0w);
        A1x = fmaf(hb.x, nb, A1x); A1y = fmaf(hb.y, nb, A1y);
        A1z = fmaf(hb.z, nb, A1z); A1w = fmaf(hb.w, nb, A1w);
    }
    if (e < e1) {
        int2 ea = csr[e];
        float na = __int_as_float(ea.y);
        float4 ha = h4[(size_t)ea.x * 16];
        A0x = fmaf(ha.x, na, A0x); A0y = fmaf(ha.y, na, A0y);
        A0z = fmaf(ha.z, na, A0z); A0w = fmaf(ha.w, na, A0w);
    }
    float4 r;
    r.x = (A0x + A1x) + (A2x + A3x);
    r.y = (A0y + A1y) + (A2y + A3y);
    r.z = (A0z + A1z) + (A2z + A3z);
    r.w = (A0w + A1w) + (A2w + A3w);
    ((float4*)agg)[(size_t)i * 16 + q] = r;
}

// ---------------------------------------------------------------- BN stats / params
__global__ void k_stats(const float* __restrict__ agg, float* __restrict__ stats) {
    const int c = threadIdx.x & 63;
    float s = 0.f, ss = 0.f;
    for (int r = blockIdx.x * 4 + (threadIdx.x >> 6); r < NNODES; r += gridDim.x * 4) {
        float v = agg[(size_t)r * 64 + c];
        s += v;
        ss = fmaf(v, v, ss);
    }
    __shared__ float ls[256], lss[256];
    ls[threadIdx.x] = s;
    lss[threadIdx.x] = ss;
    __syncthreads();
    if (threadIdx.x < 64) {
        s = ls[c] + ls[c + 64] + ls[c + 128] + ls[c + 192];
        ss = lss[c] + lss[c + 64] + lss[c + 128] + lss[c + 192];
        unsafeAtomicAdd(&stats[c], s);
        unsafeAtomicAdd(&stats[64 + c], ss);
    }
}

__global__ void k_bnparams(const float* __restrict__ stats, const float* __restrict__ g,
                           const float* __restrict__ be, float* __restrict__ scale,
                           float* __restrict__ shift) {
    int c = threadIdx.x;
    if (c < 64) {
        float mu = stats[c] * (1.0f / NNODES);
        float var = stats[64 + c] * (1.0f / NNODES) - mu * mu;
        float sc = g[c] * rsqrtf(var + EPSV);
        scale[c] = sc;
        shift[c] = fmaf(-mu, sc, be[c]);
    }
}

// ---------------------------------------------------------------- pool + final
__global__ void k_pool(const float* __restrict__ agg, const float* __restrict__ scale,
                       const float* __restrict__ shift, const int* __restrict__ batch,
                       float* __restrict__ pooled, float* __restrict__ cnt) {
    int t = blockIdx.x * 256 + threadIdx.x;
    if (t >= NNODES * DH) return;
    int i = t >> 6, c = t & 63;
    float v = fmaxf(fmaf(agg[t], scale[c], shift[c]), 0.0f);
    int g = batch[i];
    unsafeAtomicAdd(&pooled[(size_t)g * 64 + c], v);
    if (c == 0) unsafeAtomicAdd(&cnt[g], 1.0f);
}

__global__ void k_final(const float* __restrict__ pooled, const float* __restrict__ cnt,
                        const float* __restrict__ Wfc, const float* __restrict__ bfc,
                        float* __restrict__ out) {
    __shared__ float p[64];
    __shared__ float ic;
    int g = blockIdx.x, tid = threadIdx.x;
    p[tid] = pooled[(size_t)g * 64 + tid];
    if (tid == 0) ic = 1.0f / fmaxf(cnt[g], 1.0f);
    __syncthreads();
    if (tid < DOUT) {
        float a = bfc[tid];
#pragma unroll 8
        for (int c = 0; c < 64; ++c) a = fmaf(p[c] * ic, Wfc[c * DOUT + tid], a);
        out[g * DOUT + tid] = a;
    }
}

// ---------------------------------------------------------------- launch
extern "C" void kernel_launch(void* const* d_in, const int* in_sizes, int n_in,
                              void* d_out, int out_size, void* d_ws, size_t ws_size,
                              hipStream_t stream) {
    const float* x = (const float*)d_in[0];
    const int* ei = (const int*)d_in[1];
    const int* batch = (const int*)d_in[2];
    const int* srcE = ei;
    const int* dstE = ei + NEDGES;
    const float* W[3] = {(const float*)d_in[3], (const float*)d_in[7], (const float*)d_in[11]};
    const float* B[3] = {(const float*)d_in[4], (const float*)d_in[8], (const float*)d_in[12]};
    const float* Gm[3] = {(const float*)d_in[5], (const float*)d_in[9], (const float*)d_in[13]};
    const float* Be[3] = {(const float*)d_in[6], (const float*)d_in[10], (const float*)d_in[14]};
    const float* Wfc = (const float*)d_in[15];
    const float* bfc = (const float*)d_in[16];
    float* out = (float*)d_out;

    float* f = (float*)d_ws;
    float* dinv = f;                            // 100000
    int* cntdeg = (int*)(f + 100000);           // 100000
    int* rowptr = (int*)(f + 200000);           // 100016 (padded)
    int* cursor = (int*)(f + 300016);           // 100000
    int2* csr = (int2*)(f + 400016);            // 1.6M int2
    float* h = f + 3600016;                     // 6.4M
    float* agg = h + (size_t)NNODES * DH;       // 6.4M
    float* stats = agg + (size_t)NNODES * DH;   // 384 (3 layers x 128)
    float* scale = stats + 384;                 // 64
    float* shift = scale + 64;                  // 64
    float* pooled = shift + 64;                 // 32768
    float* cnt = pooled + NG * DH;              // 512
    short* wf = (short*)(cnt + NG);             // 3*8192 shorts = 12288 floats
    int* bsum = (int*)((float*)(cnt + NG) + 12288);  // 400
    int* boff = bsum + 400;                     // 400

    k_zero<<<(NNODES + 255) / 256, 256, 0, stream>>>(cntdeg, pooled, cnt, stats);
    k_count<<<(NEDGES / 2 + 255) / 256, 256, 0, stream>>>(dstE, cntdeg);
    k_scan1<<<SCAN_BLKS, 256, 0, stream>>>(cntdeg, bsum, dinv);
    k_scan2<<<1, 512, 0, stream>>>(bsum, boff);
    k_scan3<<<SCAN_BLKS, 256, 0, stream>>>(cntdeg, boff, rowptr, cursor);
    k_fill<<<(NEDGES + 255) / 256, 256, 0, stream>>>(srcE, dstE, dinv, cursor, csr);
    k_wprep<<<6, 256, 0, stream>>>(W[0], W[1], W[2], wf);

    const int gemm_grid = (NNODES + 63) / 64;
    for (int l = 0; l < 3; ++l) {
        const float* in = (l == 0) ? x : agg;
        if (l == 0)
            k_mgemm<0><<<gemm_grid, 256, 0, stream>>>(in, wf + l * 8192, scale, shift, h);
        else
            k_mgemm<1><<<gemm_grid, 256, 0, stream>>>(in, wf + l * 8192, scale, shift, h);
        k_gather<<<(NNODES * 16 + 255) / 256, 256, 0, stream>>>(h, csr, rowptr, dinv, B[l], agg);
        k_stats<<<512, 256, 0, stream>>>(agg, stats + l * 128);
        k_bnparams<<<1, 64, 0, stream>>>(stats + l * 128, Gm[l], Be[l], scale, shift);
    }

    k_pool<<<(NNODES * DH + 255) / 256, 256, 0, stream>>>(agg, scale, shift, batch, pooled, cnt);
    k_final<<<NG, 64, 0, stream>>>(pooled, cnt, Wfc, bfc, out);
}

// Round 7
// 645.178 us; speedup vs baseline: 8.8147x; 1.2698x over previous
//
#include <hip/hip_runtime.h>

#define NNODES 100000
#define NEDGES 1600000
#define DH 64
#define NG 512
#define DOUT 10
#define EPSV 1e-5f
#define SCAN_BLKS 391  // ceil(100000/256)
#define PCH 128        // nodes per pool block

typedef short bf16x8 __attribute__((ext_vector_type(8)));
typedef float f32x4 __attribute__((ext_vector_type(4)));

__device__ inline unsigned bf16_rne(float x) {
    unsigned u = __float_as_uint(x);
    return (u + 0x7fffu + ((u >> 16) & 1u)) >> 16;
}

// ---------------------------------------------------------------- init / CSR build
__global__ void k_zero(int* __restrict__ cntdeg, float* __restrict__ pooled,
                       int* __restrict__ gstart, int* __restrict__ gend,
                       float* __restrict__ stats) {
    int i = blockIdx.x * 256 + threadIdx.x;
    if (i < NNODES) cntdeg[i] = 0;
    if (i < NG * DH) pooled[i] = 0.0f;
    if (i < NG) { gstart[i] = 0; gend[i] = 0; }
    if (i < 384) stats[i] = 0.0f;  // 3 layers x (sum,sumsq)
}

__global__ void k_count(const int* __restrict__ dstE, int* __restrict__ cntdeg) {
    int e2 = blockIdx.x * 256 + threadIdx.x;
    if (e2 * 2 + 1 < NEDGES) {
        int2 d = ((const int2*)dstE)[e2];
        atomicAdd(&cntdeg[d.x], 1);
        atomicAdd(&cntdeg[d.y], 1);
    } else if (e2 * 2 < NEDGES) {
        atomicAdd(&cntdeg[dstE[e2 * 2]], 1);
    }
}

// segment boundaries of sorted batch -> per-graph node counts
__global__ void k_cnt(const int* __restrict__ batch, int* __restrict__ gstart,
                      int* __restrict__ gend) {
    int i = blockIdx.x * 256 + threadIdx.x;
    if (i >= NNODES) return;
    int g = batch[i];
    if (i == 0 || batch[i - 1] != g) gstart[g] = i;
    if (i == NNODES - 1 || batch[i + 1] != g) gend[g] = i + 1;
}

// stage 1: per-block sums (+ dinv)
__global__ void k_scan1(const int* __restrict__ cntdeg, int* __restrict__ bsum,
                        float* __restrict__ dinv) {
    __shared__ int ls[256];
    int t = threadIdx.x, i = blockIdx.x * 256 + t;
    int v = (i < NNODES) ? cntdeg[i] : 0;
    if (i < NNODES) dinv[i] = rsqrtf(1.0f + (float)v);
    ls[t] = v;
    __syncthreads();
#pragma unroll
    for (int off = 128; off > 0; off >>= 1) {
        if (t < off) ls[t] += ls[t + off];
        __syncthreads();
    }
    if (t == 0) bsum[blockIdx.x] = ls[0];
}

// stage 2: single-block scan of 391 block sums -> exclusive offsets
__global__ void __launch_bounds__(512) k_scan2(const int* __restrict__ bsum,
                                               int* __restrict__ boff) {
    __shared__ int ps[512];
    int t = threadIdx.x;
    int v = (t < SCAN_BLKS) ? bsum[t] : 0;
    ps[t] = v;
    __syncthreads();
#pragma unroll
    for (int off = 1; off < 512; off <<= 1) {
        int u = (t >= off) ? ps[t - off] : 0;
        __syncthreads();
        ps[t] += u;
        __syncthreads();
    }
    if (t < SCAN_BLKS) boff[t] = ps[t] - v;
}

// stage 3: per-block local scan + offset -> rowptr, cursor
__global__ void k_scan3(const int* __restrict__ cntdeg, const int* __restrict__ boff,
                        int* __restrict__ rowptr, int* __restrict__ cursor) {
    __shared__ int ps[256];
    int t = threadIdx.x, i = blockIdx.x * 256 + t;
    int v = (i < NNODES) ? cntdeg[i] : 0;
    ps[t] = v;
    __syncthreads();
#pragma unroll
    for (int off = 1; off < 256; off <<= 1) {
        int u = (t >= off) ? ps[t - off] : 0;
        __syncthreads();
        ps[t] += u;
        __syncthreads();
    }
    if (i < NNODES) {
        int ex = boff[blockIdx.x] + ps[t] - v;
        rowptr[i] = ex;
        cursor[i] = ex;
    }
    if (i == 0) rowptr[NNODES] = NEDGES;
}

__global__ void k_fill(const int* __restrict__ srcE, const int* __restrict__ dstE,
                       const float* __restrict__ dinv, int* __restrict__ cursor,
                       int2* __restrict__ csr) {
    int e = blockIdx.x * 256 + threadIdx.x;
    if (e >= NEDGES) return;
    int s = srcE[e], d = dstE[e];
    int pos = atomicAdd(&cursor[d], 1);
    float nm = dinv[s] * dinv[d];
    csr[pos] = make_int2(s, __float_as_int(nm));
}

// ---------------------------------------------------------------- W fragment prep
__global__ void k_wprep(const float* __restrict__ W0, const float* __restrict__ W1,
                        const float* __restrict__ W2, short* __restrict__ wf) {
    int t = blockIdx.x * 256 + threadIdx.x;  // [0, 1536)
    if (t >= 1536) return;
    int layer = t >> 9;
    int rem = t & 511;
    int ct = rem >> 7, ks = (rem >> 6) & 1, lane = rem & 63;
    const float* W = (layer == 0) ? W0 : (layer == 1) ? W1 : W2;
    short* hi = wf + layer * 8192 + rem * 8;
    short* lo = hi + 4096;
#pragma unroll
    for (int i = 0; i < 8; ++i) {
        int k = ks * 32 + ((lane >> 4) << 3) + i;
        int n = ct * 16 + (lane & 15);
        float v = W[k * 64 + n];
        unsigned h = bf16_rne(v);
        float fh = __uint_as_float(h << 16);
        unsigned l = bf16_rne(v - fh);
        hi[i] = (short)h;
        lo[i] = (short)l;
    }
}

// ---------------------------------------------------------------- MFMA GEMM
template <int AFFINE>
__global__ void __launch_bounds__(256) k_mgemm(const float* __restrict__ in,
        const short* __restrict__ wf, const float* __restrict__ scale,
        const float* __restrict__ shift, float* __restrict__ out) {
    const int tid = threadIdx.x;
    const int wv = tid >> 6, l = tid & 63;
    const int r0 = blockIdx.x * 64 + wv * 16;
    const int row = r0 + (l & 15);
    const int kq = (l >> 4) << 3;  // 0,8,16,24

    float a[2][8];
    if (row < NNODES) {
        const float* rp = in + (size_t)row * 64 + kq;
        *(float4*)&a[0][0] = *(const float4*)(rp);
        *(float4*)&a[0][4] = *(const float4*)(rp + 4);
        *(float4*)&a[1][0] = *(const float4*)(rp + 32);
        *(float4*)&a[1][4] = *(const float4*)(rp + 36);
    } else {
#pragma unroll
        for (int ks = 0; ks < 2; ++ks)
#pragma unroll
            for (int i = 0; i < 8; ++i) a[ks][i] = 0.0f;
    }
    if (AFFINE) {
#pragma unroll
        for (int ks = 0; ks < 2; ++ks) {
            float4 sc0 = *(const float4*)(scale + kq + ks * 32);
            float4 sc1 = *(const float4*)(scale + kq + ks * 32 + 4);
            float4 sh0 = *(const float4*)(shift + kq + ks * 32);
            float4 sh1 = *(const float4*)(shift + kq + ks * 32 + 4);
            a[ks][0] = fmaxf(fmaf(a[ks][0], sc0.x, sh0.x), 0.0f);
            a[ks][1] = fmaxf(fmaf(a[ks][1], sc0.y, sh0.y), 0.0f);
            a[ks][2] = fmaxf(fmaf(a[ks][2], sc0.z, sh0.z), 0.0f);
            a[ks][3] = fmaxf(fmaf(a[ks][3], sc0.w, sh0.w), 0.0f);
            a[ks][4] = fmaxf(fmaf(a[ks][4], sc1.x, sh1.x), 0.0f);
            a[ks][5] = fmaxf(fmaf(a[ks][5], sc1.y, sh1.y), 0.0f);
            a[ks][6] = fmaxf(fmaf(a[ks][6], sc1.z, sh1.z), 0.0f);
            a[ks][7] = fmaxf(fmaf(a[ks][7], sc1.w, sh1.w), 0.0f);
        }
    }

    bf16x8 ah[2], al[2];
#pragma unroll
    for (int ks = 0; ks < 2; ++ks)
#pragma unroll
        for (int i = 0; i < 8; ++i) {
            unsigned h = bf16_rne(a[ks][i]);
            float fh = __uint_as_float(h << 16);
            ah[ks][i] = (short)h;
            al[ks][i] = (short)bf16_rne(a[ks][i] - fh);
        }

    const int rb = r0 + ((l >> 4) << 2);
    const int cb = l & 15;
#pragma unroll
    for (int ct = 0; ct < 4; ++ct) {
        const short* base = wf + (ct * 128 + l) * 8;
        bf16x8 wh0 = *(const bf16x8*)(base);
        bf16x8 wh1 = *(const bf16x8*)(base + 64 * 8);
        bf16x8 wl0 = *(const bf16x8*)(base + 4096);
        bf16x8 wl1 = *(const bf16x8*)(base + 4096 + 64 * 8);
        f32x4 acc = {0.0f, 0.0f, 0.0f, 0.0f};
        acc = __builtin_amdgcn_mfma_f32_16x16x32_bf16(ah[0], wh0, acc, 0, 0, 0);
        acc = __builtin_amdgcn_mfma_f32_16x16x32_bf16(ah[1], wh1, acc, 0, 0, 0);
        acc = __builtin_amdgcn_mfma_f32_16x16x32_bf16(al[0], wh0, acc, 0, 0, 0);
        acc = __builtin_amdgcn_mfma_f32_16x16x32_bf16(al[1], wh1, acc, 0, 0, 0);
        acc = __builtin_amdgcn_mfma_f32_16x16x32_bf16(ah[0], wl0, acc, 0, 0, 0);
        acc = __builtin_amdgcn_mfma_f32_16x16x32_bf16(ah[1], wl1, acc, 0, 0, 0);
        int n = ct * 16 + cb;
#pragma unroll
        for (int r = 0; r < 4; ++r)
            if (rb + r < NNODES) out[(size_t)(rb + r) * 64 + n] = acc[r];
    }
}

// ---------------------------------------------------------------- gather (CSR), unroll 4
__global__ void k_gather(const float* __restrict__ h, const int2* __restrict__ csr,
                         const int* __restrict__ rowptr, const float* __restrict__ dinv,
                         const float* __restrict__ bias, float* __restrict__ agg) {
    int t = blockIdx.x * 256 + threadIdx.x;
    int i = t >> 4, q = t & 15;
    if (i >= NNODES) return;
    const float4* h4 = (const float4*)h + q;
    float dv = dinv[i];
    float sn = dv * dv;
    float4 a = h4[(size_t)i * 16];
    float4 bq = ((const float4*)bias)[q];
    float A0x = fmaf(a.x, sn, bq.x), A0y = fmaf(a.y, sn, bq.y);
    float A0z = fmaf(a.z, sn, bq.z), A0w = fmaf(a.w, sn, bq.w);
    float A1x = 0.f, A1y = 0.f, A1z = 0.f, A1w = 0.f;
    float A2x = 0.f, A2y = 0.f, A2z = 0.f, A2w = 0.f;
    float A3x = 0.f, A3y = 0.f, A3z = 0.f, A3w = 0.f;
    int e0 = rowptr[i], e1 = rowptr[i + 1];
    int e = e0;
    for (; e + 4 <= e1; e += 4) {
        int2 ea = csr[e], eb = csr[e + 1], ec = csr[e + 2], ed = csr[e + 3];
        float na = __int_as_float(ea.y), nb = __int_as_float(eb.y);
        float nc = __int_as_float(ec.y), nd = __int_as_float(ed.y);
        float4 ha = h4[(size_t)ea.x * 16];
        float4 hb = h4[(size_t)eb.x * 16];
        float4 hc = h4[(size_t)ec.x * 16];
        float4 hd = h4[(size_t)ed.x * 16];
        A0x = fmaf(ha.x, na, A0x); A0y = fmaf(ha.y, na, A0y);
        A0z = fmaf(ha.z, na, A0z); A0w = fmaf(ha.w, na, A0w);
        A1x = fmaf(hb.x, nb, A1x); A1y = fmaf(hb.y, nb, A1y);
        A1z = fmaf(hb.z, nb, A1z); A1w = fmaf(hb.w, nb, A1w);
        A2x = fmaf(hc.x, nc, A2x); A2y = fmaf(hc.y, nc, A2y);
        A2z = fmaf(hc.z, nc, A2z); A2w = fmaf(hc.w, nc, A2w);
        A3x = fmaf(hd.x, nd, A3x); A3y = fmaf(hd.y, nd, A3y);
        A3z = fmaf(hd.z, nd, A3z); A3w = fmaf(hd.w, nd, A3w);
    }
    for (; e + 2 <= e1; e += 2) {
        int2 ea = csr[e], eb = csr[e + 1];
        float na = __int_as_float(ea.y), nb = __int_as_float(eb.y);
        float4 ha = h4[(size_t)ea.x * 16];
        float4 hb = h4[(size_t)eb.x * 16];
        A0x = fmaf(ha.x, na, A0x); A0y = fmaf(ha.y, na, A0y);
        A0z = fmaf(ha.z, na, A0z); A0w = fmaf(ha.w, na, A0w);
        A1x = fmaf(hb.x, nb, A1x); A1y = fmaf(hb.y, nb, A1y);
        A1z = fmaf(hb.z, nb, A1z); A1w = fmaf(hb.w, nb, A1w);
    }
    if (e < e1) {
        int2 ea = csr[e];
        float na = __int_as_float(ea.y);
        float4 ha = h4[(size_t)ea.x * 16];
        A0x = fmaf(ha.x, na, A0x); A0y = fmaf(ha.y, na, A0y);
        A0z = fmaf(ha.z, na, A0z); A0w = fmaf(ha.w, na, A0w);
    }
    float4 r;
    r.x = (A0x + A1x) + (A2x + A3x);
    r.y = (A0y + A1y) + (A2y + A3y);
    r.z = (A0z + A1z) + (A2z + A3z);
    r.w = (A0w + A1w) + (A2w + A3w);
    ((float4*)agg)[(size_t)i * 16 + q] = r;
}

// ---------------------------------------------------------------- BN stats / params
__global__ void k_stats(const float* __restrict__ agg, float* __restrict__ stats) {
    const int c = threadIdx.x & 63;
    float s = 0.f, ss = 0.f;
    for (int r = blockIdx.x * 4 + (threadIdx.x >> 6); r < NNODES; r += gridDim.x * 4) {
        float v = agg[(size_t)r * 64 + c];
        s += v;
        ss = fmaf(v, v, ss);
    }
    __shared__ float ls[256], lss[256];
    ls[threadIdx.x] = s;
    lss[threadIdx.x] = ss;
    __syncthreads();
    if (threadIdx.x < 64) {
        s = ls[c] + ls[c + 64] + ls[c + 128] + ls[c + 192];
        ss = lss[c] + lss[c + 64] + lss[c + 128] + lss[c + 192];
        unsafeAtomicAdd(&stats[c], s);
        unsafeAtomicAdd(&stats[64 + c], ss);
    }
}

__global__ void k_bnparams(const float* __restrict__ stats, const float* __restrict__ g,
                           const float* __restrict__ be, float* __restrict__ scale,
                           float* __restrict__ shift) {
    int c = threadIdx.x;
    if (c < 64) {
        float mu = stats[c] * (1.0f / NNODES);
        float var = stats[64 + c] * (1.0f / NNODES) - mu * mu;
        float sc = g[c] * rsqrtf(var + EPSV);
        scale[c] = sc;
        shift[c] = fmaf(-mu, sc, be[c]);
    }
}

// ---------------------------------------------------------------- pool (sorted-batch run accumulation)
__global__ void k_pool(const float* __restrict__ agg, const float* __restrict__ scale,
                       const float* __restrict__ shift, const int* __restrict__ batch,
                       float* __restrict__ pooled) {
    const int tid = threadIdx.x;
    const int c = tid & 63, r = tid >> 6;
    const int i0 = blockIdx.x * PCH;
    const float sc = scale[c], sh = shift[c];
    float acc = 0.0f;
    int cur = -1;
#pragma unroll 4
    for (int k = 0; k < PCH / 4; ++k) {
        int i = i0 + k * 4 + r;
        if (i >= NNODES) break;
        int g = batch[i];
        if (g != cur) {
            if (cur >= 0) unsafeAtomicAdd(&pooled[cur * 64 + c], acc);
            acc = 0.0f;
            cur = g;
        }
        acc += fmaxf(fmaf(agg[(size_t)i * 64 + c], sc, sh), 0.0f);
    }
    if (cur >= 0) unsafeAtomicAdd(&pooled[cur * 64 + c], acc);
}

__global__ void k_final(const float* __restrict__ pooled, const int* __restrict__ gstart,
                        const int* __restrict__ gend, const float* __restrict__ Wfc,
                        const float* __restrict__ bfc, float* __restrict__ out) {
    __shared__ float p[64];
    __shared__ float ic;
    int g = blockIdx.x, tid = threadIdx.x;
    p[tid] = pooled[(size_t)g * 64 + tid];
    if (tid == 0) ic = 1.0f / fmaxf((float)(gend[g] - gstart[g]), 1.0f);
    __syncthreads();
    if (tid < DOUT) {
        float a = bfc[tid];
#pragma unroll 8
        for (int c = 0; c < 64; ++c) a = fmaf(p[c] * ic, Wfc[c * DOUT + tid], a);
        out[g * DOUT + tid] = a;
    }
}

// ---------------------------------------------------------------- launch
extern "C" void kernel_launch(void* const* d_in, const int* in_sizes, int n_in,
                              void* d_out, int out_size, void* d_ws, size_t ws_size,
                              hipStream_t stream) {
    const float* x = (const float*)d_in[0];
    const int* ei = (const int*)d_in[1];
    const int* batch = (const int*)d_in[2];
    const int* srcE = ei;
    const int* dstE = ei + NEDGES;
    const float* W[3] = {(const float*)d_in[3], (const float*)d_in[7], (const float*)d_in[11]};
    const float* B[3] = {(const float*)d_in[4], (const float*)d_in[8], (const float*)d_in[12]};
    const float* Gm[3] = {(const float*)d_in[5], (const float*)d_in[9], (const float*)d_in[13]};
    const float* Be[3] = {(const float*)d_in[6], (const float*)d_in[10], (const float*)d_in[14]};
    const float* Wfc = (const float*)d_in[15];
    const float* bfc = (const float*)d_in[16];
    float* out = (float*)d_out;

    float* f = (float*)d_ws;
    float* dinv = f;                            // 100000
    int* cntdeg = (int*)(f + 100000);           // 100000
    int* rowptr = (int*)(f + 200000);           // 100016 (padded)
    int* cursor = (int*)(f + 300016);           // 100000
    int2* csr = (int2*)(f + 400016);            // 1.6M int2
    float* h = f + 3600016;                     // 6.4M
    float* agg = h + (size_t)NNODES * DH;       // 6.4M
    float* stats = agg + (size_t)NNODES * DH;   // 384 (3 layers x 128)
    float* scale = stats + 384;                 // 64
    float* shift = scale + 64;                  // 64
    float* pooled = shift + 64;                 // 32768
    int* gstart = (int*)(pooled + NG * DH);     // 512
    int* gend = gstart + NG;                    // 512
    short* wf = (short*)(gend + NG);            // 3*8192 shorts
    int* bsum = (int*)((short*)wf + 24576);     // 400
    int* boff = bsum + 400;                     // 400

    k_zero<<<(NNODES + 255) / 256, 256, 0, stream>>>(cntdeg, pooled, gstart, gend, stats);
    k_count<<<(NEDGES / 2 + 255) / 256, 256, 0, stream>>>(dstE, cntdeg);
    k_cnt<<<(NNODES + 255) / 256, 256, 0, stream>>>(batch, gstart, gend);
    k_scan1<<<SCAN_BLKS, 256, 0, stream>>>(cntdeg, bsum, dinv);
    k_scan2<<<1, 512, 0, stream>>>(bsum, boff);
    k_scan3<<<SCAN_BLKS, 256, 0, stream>>>(cntdeg, boff, rowptr, cursor);
    k_fill<<<(NEDGES + 255) / 256, 256, 0, stream>>>(srcE, dstE, dinv, cursor, csr);
    k_wprep<<<6, 256, 0, stream>>>(W[0], W[1], W[2], wf);

    const int gemm_grid = (NNODES + 63) / 64;
    for (int l = 0; l < 3; ++l) {
        const float* in = (l == 0) ? x : agg;
        if (l == 0)
            k_mgemm<0><<<gemm_grid, 256, 0, stream>>>(in, wf + l * 8192, scale, shift, h);
        else
            k_mgemm<1><<<gemm_grid, 256, 0, stream>>>(in, wf + l * 8192, scale, shift, h);
        k_gather<<<(NNODES * 16 + 255) / 256, 256, 0, stream>>>(h, csr, rowptr, dinv, B[l], agg);
        k_stats<<<512, 256, 0, stream>>>(agg, stats + l * 128);
        k_bnparams<<<1, 64, 0, stream>>>(stats + l * 128, Gm[l], Be[l], scale, shift);
    }

    k_pool<<<(NNODES + PCH - 1) / PCH, 256, 0, stream>>>(agg, scale, shift, batch, pooled);
    k_final<<<NG, 64, 0, stream>>>(pooled, gstart, gend, Wfc, bfc, out);
}

// Round 8
// 549.560 us; speedup vs baseline: 10.3484x; 1.1740x over previous
//
#include <hip/hip_runtime.h>

#define NNODES 100000
#define NEDGES 1600000
#define DH 64
#define NG 512
#define DOUT 10
#define EPSV 1e-5f
#define SCAN_BLKS 391  // ceil(100000/256)
#define PCH 128        // nodes per pool block

typedef short bf16x8 __attribute__((ext_vector_type(8)));
typedef float f32x4 __attribute__((ext_vector_type(4)));

__device__ inline unsigned bf16_rne(float x) {
    unsigned u = __float_as_uint(x);
    return (u + 0x7fffu + ((u >> 16) & 1u)) >> 16;
}
__device__ inline float bflo(unsigned u) { return __uint_as_float(u << 16); }
__device__ inline float bfhi(unsigned u) { return __uint_as_float(u & 0xffff0000u); }

// ---------------------------------------------------------------- init / CSR build
__global__ void k_zero(int* __restrict__ cntdeg, float* __restrict__ pooled,
                       int* __restrict__ gstart, int* __restrict__ gend,
                       float* __restrict__ stats) {
    int i = blockIdx.x * 256 + threadIdx.x;
    if (i < NNODES) cntdeg[i] = 0;
    if (i < NG * DH) pooled[i] = 0.0f;
    if (i < NG) { gstart[i] = 0; gend[i] = 0; }
    if (i < 384) stats[i] = 0.0f;  // 3 layers x (sum,sumsq)
}

__global__ void k_count(const int* __restrict__ dstE, int* __restrict__ cntdeg) {
    int e2 = blockIdx.x * 256 + threadIdx.x;
    if (e2 * 2 + 1 < NEDGES) {
        int2 d = ((const int2*)dstE)[e2];
        atomicAdd(&cntdeg[d.x], 1);
        atomicAdd(&cntdeg[d.y], 1);
    } else if (e2 * 2 < NEDGES) {
        atomicAdd(&cntdeg[dstE[e2 * 2]], 1);
    }
}

// stage 1: per-block sums (+ dinv, + batch segment boundaries)
__global__ void k_scan1(const int* __restrict__ cntdeg, int* __restrict__ bsum,
                        float* __restrict__ dinv, const int* __restrict__ batch,
                        int* __restrict__ gstart, int* __restrict__ gend) {
    __shared__ int ls[256];
    int t = threadIdx.x, i = blockIdx.x * 256 + t;
    int v = (i < NNODES) ? cntdeg[i] : 0;
    if (i < NNODES) {
        dinv[i] = rsqrtf(1.0f + (float)v);
        int g = batch[i];
        if (i == 0 || batch[i - 1] != g) gstart[g] = i;
        if (i == NNODES - 1 || batch[i + 1] != g) gend[g] = i + 1;
    }
    ls[t] = v;
    __syncthreads();
#pragma unroll
    for (int off = 128; off > 0; off >>= 1) {
        if (t < off) ls[t] += ls[t + off];
        __syncthreads();
    }
    if (t == 0) bsum[blockIdx.x] = ls[0];
}

// stage 2: single-block scan of 391 block sums -> exclusive offsets
__global__ void __launch_bounds__(512) k_scan2(const int* __restrict__ bsum,
                                               int* __restrict__ boff) {
    __shared__ int ps[512];
    int t = threadIdx.x;
    int v = (t < SCAN_BLKS) ? bsum[t] : 0;
    ps[t] = v;
    __syncthreads();
#pragma unroll
    for (int off = 1; off < 512; off <<= 1) {
        int u = (t >= off) ? ps[t - off] : 0;
        __syncthreads();
        ps[t] += u;
        __syncthreads();
    }
    if (t < SCAN_BLKS) boff[t] = ps[t] - v;
}

// stage 3: per-block local scan + offset -> rowptr, cursor
__global__ void k_scan3(const int* __restrict__ cntdeg, const int* __restrict__ boff,
                        int* __restrict__ rowptr, int* __restrict__ cursor) {
    __shared__ int ps[256];
    int t = threadIdx.x, i = blockIdx.x * 256 + t;
    int v = (i < NNODES) ? cntdeg[i] : 0;
    ps[t] = v;
    __syncthreads();
#pragma unroll
    for (int off = 1; off < 256; off <<= 1) {
        int u = (t >= off) ? ps[t - off] : 0;
        __syncthreads();
        ps[t] += u;
        __syncthreads();
    }
    if (i < NNODES) {
        int ex = boff[blockIdx.x] + ps[t] - v;
        rowptr[i] = ex;
        cursor[i] = ex;
    }
    if (i == 0) rowptr[NNODES] = NEDGES;
}

__global__ void k_fill(const int* __restrict__ srcE, const int* __restrict__ dstE,
                       const float* __restrict__ dinv, int* __restrict__ cursor,
                       int2* __restrict__ csr) {
    int e = blockIdx.x * 256 + threadIdx.x;
    if (e >= NEDGES) return;
    int s = srcE[e], d = dstE[e];
    int pos = atomicAdd(&cursor[d], 1);
    float nm = dinv[s] * dinv[d];
    csr[pos] = make_int2(s, __float_as_int(nm));
}

// ---------------------------------------------------------------- W fragment prep
__global__ void k_wprep(const float* __restrict__ W0, const float* __restrict__ W1,
                        const float* __restrict__ W2, short* __restrict__ wf) {
    int t = blockIdx.x * 256 + threadIdx.x;  // [0, 1536)
    if (t >= 1536) return;
    int layer = t >> 9;
    int rem = t & 511;
    int ct = rem >> 7, ks = (rem >> 6) & 1, lane = rem & 63;
    const float* W = (layer == 0) ? W0 : (layer == 1) ? W1 : W2;
    short* hi = wf + layer * 8192 + rem * 8;
    short* lo = hi + 4096;
#pragma unroll
    for (int i = 0; i < 8; ++i) {
        int k = ks * 32 + ((lane >> 4) << 3) + i;
        int n = ct * 16 + (lane & 15);
        float v = W[k * 64 + n];
        unsigned h = bf16_rne(v);
        float fh = __uint_as_float(h << 16);
        unsigned l = bf16_rne(v - fh);
        hi[i] = (short)h;
        lo[i] = (short)l;
    }
}

// ---------------------------------------------------------------- MFMA GEMM (bf16 output)
template <int AFFINE>
__global__ void __launch_bounds__(256) k_mgemm(const float* __restrict__ in,
        const short* __restrict__ wf, const float* __restrict__ scale,
        const float* __restrict__ shift, unsigned short* __restrict__ out) {
    const int tid = threadIdx.x;
    const int wv = tid >> 6, l = tid & 63;
    const int r0 = blockIdx.x * 64 + wv * 16;
    const int row = r0 + (l & 15);
    const int kq = (l >> 4) << 3;  // 0,8,16,24

    float a[2][8];
    if (row < NNODES) {
        const float* rp = in + (size_t)row * 64 + kq;
        *(float4*)&a[0][0] = *(const float4*)(rp);
        *(float4*)&a[0][4] = *(const float4*)(rp + 4);
        *(float4*)&a[1][0] = *(const float4*)(rp + 32);
        *(float4*)&a[1][4] = *(const float4*)(rp + 36);
    } else {
#pragma unroll
        for (int ks = 0; ks < 2; ++ks)
#pragma unroll
            for (int i = 0; i < 8; ++i) a[ks][i] = 0.0f;
    }
    if (AFFINE) {
#pragma unroll
        for (int ks = 0; ks < 2; ++ks) {
            float4 sc0 = *(const float4*)(scale + kq + ks * 32);
            float4 sc1 = *(const float4*)(scale + kq + ks * 32 + 4);
            float4 sh0 = *(const float4*)(shift + kq + ks * 32);
            float4 sh1 = *(const float4*)(shift + kq + ks * 32 + 4);
            a[ks][0] = fmaxf(fmaf(a[ks][0], sc0.x, sh0.x), 0.0f);
            a[ks][1] = fmaxf(fmaf(a[ks][1], sc0.y, sh0.y), 0.0f);
            a[ks][2] = fmaxf(fmaf(a[ks][2], sc0.z, sh0.z), 0.0f);
            a[ks][3] = fmaxf(fmaf(a[ks][3], sc0.w, sh0.w), 0.0f);
            a[ks][4] = fmaxf(fmaf(a[ks][4], sc1.x, sh1.x), 0.0f);
            a[ks][5] = fmaxf(fmaf(a[ks][5], sc1.y, sh1.y), 0.0f);
            a[ks][6] = fmaxf(fmaf(a[ks][6], sc1.z, sh1.z), 0.0f);
            a[ks][7] = fmaxf(fmaf(a[ks][7], sc1.w, sh1.w), 0.0f);
        }
    }

    bf16x8 ah[2], al[2];
#pragma unroll
    for (int ks = 0; ks < 2; ++ks)
#pragma unroll
        for (int i = 0; i < 8; ++i) {
            unsigned h = bf16_rne(a[ks][i]);
            float fh = __uint_as_float(h << 16);
            ah[ks][i] = (short)h;
            al[ks][i] = (short)bf16_rne(a[ks][i] - fh);
        }

    const int rb = r0 + ((l >> 4) << 2);
    const int cb = l & 15;
#pragma unroll
    for (int ct = 0; ct < 4; ++ct) {
        const short* base = wf + (ct * 128 + l) * 8;
        bf16x8 wh0 = *(const bf16x8*)(base);
        bf16x8 wh1 = *(const bf16x8*)(base + 64 * 8);
        bf16x8 wl0 = *(const bf16x8*)(base + 4096);
        bf16x8 wl1 = *(const bf16x8*)(base + 4096 + 64 * 8);
        f32x4 acc = {0.0f, 0.0f, 0.0f, 0.0f};
        acc = __builtin_amdgcn_mfma_f32_16x16x32_bf16(ah[0], wh0, acc, 0, 0, 0);
        acc = __builtin_amdgcn_mfma_f32_16x16x32_bf16(ah[1], wh1, acc, 0, 0, 0);
        acc = __builtin_amdgcn_mfma_f32_16x16x32_bf16(al[0], wh0, acc, 0, 0, 0);
        acc = __builtin_amdgcn_mfma_f32_16x16x32_bf16(al[1], wh1, acc, 0, 0, 0);
        acc = __builtin_amdgcn_mfma_f32_16x16x32_bf16(ah[0], wl0, acc, 0, 0, 0);
        acc = __builtin_amdgcn_mfma_f32_16x16x32_bf16(ah[1], wl1, acc, 0, 0, 0);
        int n = ct * 16 + cb;
#pragma unroll
        for (int r = 0; r < 4; ++r)
            if (rb + r < NNODES) out[(size_t)(rb + r) * 64 + n] = (unsigned short)bf16_rne(acc[r]);
    }
}

// ---------------------------------------------------------------- gather (CSR, bf16 h)
// 8 lanes/node, uint4 = 8 bf16 feats per lane. Unroll 4, two accumulator banks.
__global__ void k_gather(const uint4* __restrict__ h, const int2* __restrict__ csr,
                         const int* __restrict__ rowptr, const float* __restrict__ dinv,
                         const float* __restrict__ bias, float* __restrict__ agg) {
    int t = blockIdx.x * 256 + threadIdx.x;
    int i = t >> 3, q = t & 7;
    if (i >= NNODES) return;
    float dv = dinv[i];
    float sn = dv * dv;
    float4 b0 = ((const float4*)bias)[q * 2];
    float4 b1 = ((const float4*)bias)[q * 2 + 1];
    uint4 hv = h[(size_t)i * 8 + q];
    float A[8], B[8];
    A[0] = fmaf(bflo(hv.x), sn, b0.x); A[1] = fmaf(bfhi(hv.x), sn, b0.y);
    A[2] = fmaf(bflo(hv.y), sn, b0.z); A[3] = fmaf(bfhi(hv.y), sn, b0.w);
    A[4] = fmaf(bflo(hv.z), sn, b1.x); A[5] = fmaf(bfhi(hv.z), sn, b1.y);
    A[6] = fmaf(bflo(hv.w), sn, b1.z); A[7] = fmaf(bfhi(hv.w), sn, b1.w);
#pragma unroll
    for (int k = 0; k < 8; ++k) B[k] = 0.0f;

    int e0 = rowptr[i], e1 = rowptr[i + 1];
    int e = e0;
    for (; e + 4 <= e1; e += 4) {
        int2 ea = csr[e], eb = csr[e + 1], ec = csr[e + 2], ed = csr[e + 3];
        float na = __int_as_float(ea.y), nb = __int_as_float(eb.y);
        float nc = __int_as_float(ec.y), nd = __int_as_float(ed.y);
        uint4 va = h[(size_t)ea.x * 8 + q];
        uint4 vb = h[(size_t)eb.x * 8 + q];
        uint4 vc = h[(size_t)ec.x * 8 + q];
        uint4 vd = h[(size_t)ed.x * 8 + q];
        A[0] = fmaf(bflo(va.x), na, A[0]); A[1] = fmaf(bfhi(va.x), na, A[1]);
        A[2] = fmaf(bflo(va.y), na, A[2]); A[3] = fmaf(bfhi(va.y), na, A[3]);
        A[4] = fmaf(bflo(va.z), na, A[4]); A[5] = fmaf(bfhi(va.z), na, A[5]);
        A[6] = fmaf(bflo(va.w), na, A[6]); A[7] = fmaf(bfhi(va.w), na, A[7]);
        B[0] = fmaf(bflo(vb.x), nb, B[0]); B[1] = fmaf(bfhi(vb.x), nb, B[1]);
        B[2] = fmaf(bflo(vb.y), nb, B[2]); B[3] = fmaf(bfhi(vb.y), nb, B[3]);
        B[4] = fmaf(bflo(vb.z), nb, B[4]); B[5] = fmaf(bfhi(vb.z), nb, B[5]);
        B[6] = fmaf(bflo(vb.w), nb, B[6]); B[7] = fmaf(bfhi(vb.w), nb, B[7]);
        A[0] = fmaf(bflo(vc.x), nc, A[0]); A[1] = fmaf(bfhi(vc.x), nc, A[1]);
        A[2] = fmaf(bflo(vc.y), nc, A[2]); A[3] = fmaf(bfhi(vc.y), nc, A[3]);
        A[4] = fmaf(bflo(vc.z), nc, A[4]); A[5] = fmaf(bfhi(vc.z), nc, A[5]);
        A[6] = fmaf(bflo(vc.w), nc, A[6]); A[7] = fmaf(bfhi(vc.w), nc, A[7]);
        B[0] = fmaf(bflo(vd.x), nd, B[0]); B[1] = fmaf(bfhi(vd.x), nd, B[1]);
        B[2] = fmaf(bflo(vd.y), nd, B[2]); B[3] = fmaf(bfhi(vd.y), nd, B[3]);
        B[4] = fmaf(bflo(vd.z), nd, B[4]); B[5] = fmaf(bfhi(vd.z), nd, B[5]);
        B[6] = fmaf(bflo(vd.w), nd, B[6]); B[7] = fmaf(bfhi(vd.w), nd, B[7]);
    }
    for (; e + 2 <= e1; e += 2) {
        int2 ea = csr[e], eb = csr[e + 1];
        float na = __int_as_float(ea.y), nb = __int_as_float(eb.y);
        uint4 va = h[(size_t)ea.x * 8 + q];
        uint4 vb = h[(size_t)eb.x * 8 + q];
        A[0] = fmaf(bflo(va.x), na, A[0]); A[1] = fmaf(bfhi(va.x), na, A[1]);
        A[2] = fmaf(bflo(va.y), na, A[2]); A[3] = fmaf(bfhi(va.y), na, A[3]);
        A[4] = fmaf(bflo(va.z), na, A[4]); A[5] = fmaf(bfhi(va.z), na, A[5]);
        A[6] = fmaf(bflo(va.w), na, A[6]); A[7] = fmaf(bfhi(va.w), na, A[7]);
        B[0] = fmaf(bflo(vb.x), nb, B[0]); B[1] = fmaf(bfhi(vb.x), nb, B[1]);
        B[2] = fmaf(bflo(vb.y), nb, B[2]); B[3] = fmaf(bfhi(vb.y), nb, B[3]);
        B[4] = fmaf(bflo(vb.z), nb, B[4]); B[5] = fmaf(bfhi(vb.z), nb, B[5]);
        B[6] = fmaf(bflo(vb.w), nb, B[6]); B[7] = fmaf(bfhi(vb.w), nb, B[7]);
    }
    if (e < e1) {
        int2 ea = csr[e];
        float na = __int_as_float(ea.y);
        uint4 va = h[(size_t)ea.x * 8 + q];
        A[0] = fmaf(bflo(va.x), na, A[0]); A[1] = fmaf(bfhi(va.x), na, A[1]);
        A[2] = fmaf(bflo(va.y), na, A[2]); A[3] = fmaf(bfhi(va.y), na, A[3]);
        A[4] = fmaf(bflo(va.z), na, A[4]); A[5] = fmaf(bfhi(va.z), na, A[5]);
        A[6] = fmaf(bflo(va.w), na, A[6]); A[7] = fmaf(bfhi(va.w), na, A[7]);
    }
    float4 r0, r1;
    r0.x = A[0] + B[0]; r0.y = A[1] + B[1]; r0.z = A[2] + B[2]; r0.w = A[3] + B[3];
    r1.x = A[4] + B[4]; r1.y = A[5] + B[5]; r1.z = A[6] + B[6]; r1.w = A[7] + B[7];
    ((float4*)agg)[(size_t)i * 16 + q * 2] = r0;
    ((float4*)agg)[(size_t)i * 16 + q * 2 + 1] = r1;
}

// ---------------------------------------------------------------- BN stats / params
__global__ void k_stats(const float* __restrict__ agg, float* __restrict__ stats) {
    const int c = threadIdx.x & 63;
    float s = 0.f, ss = 0.f;
    for (int r = blockIdx.x * 4 + (threadIdx.x >> 6); r < NNODES; r += gridDim.x * 4) {
        float v = agg[(size_t)r * 64 + c];
        s += v;
        ss = fmaf(v, v, ss);
    }
    __shared__ float ls[256], lss[256];
    ls[threadIdx.x] = s;
    lss[threadIdx.x] = ss;
    __syncthreads();
    if (threadIdx.x < 64) {
        s = ls[c] + ls[c + 64] + ls[c + 128] + ls[c + 192];
        ss = lss[c] + lss[c + 64] + lss[c + 128] + lss[c + 192];
        unsafeAtomicAdd(&stats[c], s);
        unsafeAtomicAdd(&stats[64 + c], ss);
    }
}

__global__ void k_bnparams(const float* __restrict__ stats, const float* __restrict__ g,
                           const float* __restrict__ be, float* __restrict__ scale,
                           float* __restrict__ shift) {
    int c = threadIdx.x;
    if (c < 64) {
        float mu = stats[c] * (1.0f / NNODES);
        float var = stats[64 + c] * (1.0f / NNODES) - mu * mu;
        float sc = g[c] * rsqrtf(var + EPSV);
        scale[c] = sc;
        shift[c] = fmaf(-mu, sc, be[c]);
    }
}

// ---------------------------------------------------------------- pool (sorted-batch run accumulation)
__global__ void k_pool(const float* __restrict__ agg, const float* __restrict__ scale,
                       const float* __restrict__ shift, const int* __restrict__ batch,
                       float* __restrict__ pooled) {
    const int tid = threadIdx.x;
    const int c = tid & 63, r = tid >> 6;
    const int i0 = blockIdx.x * PCH;
    const float sc = scale[c], sh = shift[c];
    float acc = 0.0f;
    int cur = -1;
#pragma unroll 4
    for (int k = 0; k < PCH / 4; ++k) {
        int i = i0 + k * 4 + r;
        if (i >= NNODES) break;
        int g = batch[i];
        if (g != cur) {
            if (cur >= 0) unsafeAtomicAdd(&pooled[cur * 64 + c], acc);
            acc = 0.0f;
            cur = g;
        }
        acc += fmaxf(fmaf(agg[(size_t)i * 64 + c], sc, sh), 0.0f);
    }
    if (cur >= 0) unsafeAtomicAdd(&pooled[cur * 64 + c], acc);
}

__global__ void k_final(const float* __restrict__ pooled, const int* __restrict__ gstart,
                        const int* __restrict__ gend, const float* __restrict__ Wfc,
                        const float* __restrict__ bfc, float* __restrict__ out) {
    __shared__ float p[64];
    __shared__ float ic;
    int g = blockIdx.x, tid = threadIdx.x;
    p[tid] = pooled[(size_t)g * 64 + tid];
    if (tid == 0) ic = 1.0f / fmaxf((float)(gend[g] - gstart[g]), 1.0f);
    __syncthreads();
    if (tid < DOUT) {
        float a = bfc[tid];
#pragma unroll 8
        for (int c = 0; c < 64; ++c) a = fmaf(p[c] * ic, Wfc[c * DOUT + tid], a);
        out[g * DOUT + tid] = a;
    }
}

// ---------------------------------------------------------------- launch
extern "C" void kernel_launch(void* const* d_in, const int* in_sizes, int n_in,
                              void* d_out, int out_size, void* d_ws, size_t ws_size,
                              hipStream_t stream) {
    const float* x = (const float*)d_in[0];
    const int* ei = (const int*)d_in[1];
    const int* batch = (const int*)d_in[2];
    const int* srcE = ei;
    const int* dstE = ei + NEDGES;
    const float* W[3] = {(const float*)d_in[3], (const float*)d_in[7], (const float*)d_in[11]};
    const float* B[3] = {(const float*)d_in[4], (const float*)d_in[8], (const float*)d_in[12]};
    const float* Gm[3] = {(const float*)d_in[5], (const float*)d_in[9], (const float*)d_in[13]};
    const float* Be[3] = {(const float*)d_in[6], (const float*)d_in[10], (const float*)d_in[14]};
    const float* Wfc = (const float*)d_in[15];
    const float* bfc = (const float*)d_in[16];
    float* out = (float*)d_out;

    float* f = (float*)d_ws;
    float* dinv = f;                            // 100000
    int* cntdeg = (int*)(f + 100000);           // 100000
    int* rowptr = (int*)(f + 200000);           // 100016 (padded)
    int* cursor = (int*)(f + 300016);           // 100000
    int2* csr = (int2*)(f + 400016);            // 1.6M int2
    unsigned short* h = (unsigned short*)(f + 3600016);  // 100000*64 bf16 = 3.2M floats
    float* agg = f + 3600016 + 3200000;         // 6.4M floats
    float* stats = agg + (size_t)NNODES * DH;   // 384 (3 layers x 128)
    float* scale = stats + 384;                 // 64
    float* shift = scale + 64;                  // 64
    float* pooled = shift + 64;                 // 32768
    int* gstart = (int*)(pooled + NG * DH);     // 512
    int* gend = gstart + NG;                    // 512
    short* wf = (short*)(gend + NG);            // 3*8192 shorts
    int* bsum = (int*)((short*)wf + 24576);     // 400
    int* boff = bsum + 400;                     // 400

    k_zero<<<(NNODES + 255) / 256, 256, 0, stream>>>(cntdeg, pooled, gstart, gend, stats);
    k_count<<<(NEDGES / 2 + 255) / 256, 256, 0, stream>>>(dstE, cntdeg);
    k_scan1<<<SCAN_BLKS, 256, 0, stream>>>(cntdeg, bsum, dinv, batch, gstart, gend);
    k_scan2<<<1, 512, 0, stream>>>(bsum, boff);
    k_scan3<<<SCAN_BLKS, 256, 0, stream>>>(cntdeg, boff, rowptr, cursor);
    k_fill<<<(NEDGES + 255) / 256, 256, 0, stream>>>(srcE, dstE, dinv, cursor, csr);
    k_wprep<<<6, 256, 0, stream>>>(W[0], W[1], W[2], wf);

    const int gemm_grid = (NNODES + 63) / 64;
    for (int l = 0; l < 3; ++l) {
        const float* in = (l == 0) ? x : agg;
        if (l == 0)
            k_mgemm<0><<<gemm_grid, 256, 0, stream>>>(in, wf + l * 8192, scale, shift, h);
        else
            k_mgemm<1><<<gemm_grid, 256, 0, stream>>>(in, wf + l * 8192, scale, shift, h);
        k_gather<<<(NNODES * 8 + 255) / 256, 256, 0, stream>>>((const uint4*)h, csr, rowptr, dinv, B[l], agg);
        k_stats<<<512, 256, 0, stream>>>(agg, stats + l * 128);
        k_bnparams<<<1, 64, 0, stream>>>(stats + l * 128, Gm[l], Be[l], scale, shift);
    }

    k_pool<<<(NNODES + PCH - 1) / PCH, 256, 0, stream>>>(agg, scale, shift, batch, pooled);
    k_final<<<NG, 64, 0, stream>>>(pooled, gstart, gend, Wfc, bfc, out);
}